// Round 11
// baseline (3179.061 us; speedup 1.0000x reference)
//
#include <hip/hip_runtime.h>

namespace {

constexpr int kB = 64, kSR = 29, kS = 30, kD = 768, kH = 3072, kL = 12;
constexpr int kNH = 12, kND = 14, kE = 15, kNE = 6;
constexpr int kRows = kB * kS;  // 1920
constexpr int kQKV = 2304;
constexpr long kPS = (long)kRows * kD;    // partial stride (fp32 elems)
constexpr long kPSL = (long)kRows * 128;  // lora partial stride
constexpr int kBIG = 1 << 30;

typedef __attribute__((ext_vector_type(8))) short s16x8;
typedef __attribute__((ext_vector_type(4))) float fx4;

__device__ __forceinline__ float gelu_f(float x) {
  return 0.5f * x * (1.0f + erff(x * 0.70710678118654752f));
}

__device__ __forceinline__ unsigned short f2bf_u(float x) {
  union { float f; unsigned u; } v;
  v.f = x;
  unsigned r = v.u + 0x7fffu + ((v.u >> 16) & 1u);
  return (unsigned short)(r >> 16);
}
__device__ __forceinline__ float bfu2f(unsigned short h) {
  union { unsigned u; float f; } v;
  v.u = ((unsigned)h) << 16;
  return v.f;
}

__device__ __forceinline__ void g2l16(const short* g, short* l) {
  __builtin_amdgcn_global_load_lds(
      (const __attribute__((address_space(1))) unsigned int*)g,
      (__attribute__((address_space(3))) unsigned int*)l, 16, 0, 0);
}

// XCD-aware bijective block swizzle (8 XCDs).
__device__ __forceinline__ void swz_block(int& bx, int& by, int& bz) {
  int gx = gridDim.x, gy = gridDim.y;
  int nwg = gx * gy * (int)gridDim.z;
  int orig = blockIdx.x + gx * (blockIdx.y + gy * blockIdx.z);
  int q = nwg >> 3, r = nwg & 7;
  int xcd = orig & 7, idx = orig >> 3;
  int s = (xcd < r ? xcd * (q + 1) : r * (q + 1) + (xcd - r) * q) + idx;
  bx = s % gx;
  int t2 = s / gx;
  by = t2 % gy;
  bz = t2 / gy;
}

__device__ __forceinline__ float block_sum(float v) {
  __shared__ float sb[4];
#pragma unroll
  for (int o = 32; o > 0; o >>= 1) v += __shfl_down(v, o, 64);
  int w = threadIdx.x >> 6;
  __syncthreads();
  if ((threadIdx.x & 63) == 0) sb[w] = v;
  __syncthreads();
  return sb[0] + sb[1] + sb[2] + sb[3];
}

__device__ __forceinline__ float dot8(const float* __restrict__ p,
                                      const float* __restrict__ q) {
  float4 x = *(const float4*)p;
  float4 y = *(const float4*)(p + 4);
  return x.x * q[0] + x.y * q[1] + x.z * q[2] + x.w * q[3] +
         y.x * q[4] + y.y * q[5] + y.z * q[6] + y.w * q[7];
}

// ---------------------------------------------------------------------------
// MFMA GEMM, C = A @ B^T, hi/lo bf16 planes, 3-pass (hh+hl+lh ~ fp32).
// A: row-major [M][K] planes. B: PRE-PACKED fragment-linear planes.
// Tile BMxBN, BK=32, 4 waves (2x2). SINGLE-buffered LDS (24KB at 128x64),
// m97-style loop: stage -> sync -> MFMA -> sync. High block residency
// (~5 blocks/CU) hides the drain via co-scheduled blocks (m114).
// FUSED-N: columns >= nsplit route to C2 (fp32, ldc2), no bias/act.
// MODE: 0 plain, 1 split-K partial buffers, 2 batched over bz.
// ---------------------------------------------------------------------------
template <int BM, int BN, int MODE>
__global__ __launch_bounds__(256) void gemm_hl(
    const short* __restrict__ Ah, const short* __restrict__ Al,
    const short* __restrict__ Bh, const short* __restrict__ Bl,
    const float* __restrict__ bias, float* __restrict__ Cf,
    short* __restrict__ Ch, short* __restrict__ Cl, float* __restrict__ C2,
    int K, int ldc, int ldc2, int act, int kchunk, int nsplit, long bsA,
    long bsB, long bsBias, long bsC, long bsC2) {
  constexpr int MFR = BM / 16, NFR = BN / 16;
  constexpr int NA = 2 * MFR, NB = 2 * NFR, LPW = (NA + NB) / 4;
  constexpr int MF_W = MFR / 2, NF_W = NFR / 2;
  __shared__ __align__(16) short As[2][MFR][512];
  __shared__ __align__(16) short Bs[2][NFR][512];
  int bx, by, bz;
  swz_block(bx, by, bz);
  const int t = threadIdx.x, w = t >> 6, lane = t & 63;
  const int lr = lane & 15, lg = lane >> 4;
  const int m0 = by * BM, n0 = bx * BN;
  const int kst = K >> 5;
  int k0 = 0;
  if (MODE == 1) {
    k0 = bz * kchunk;
    Cf += bz * bsC;
    C2 += bz * bsC2;
  }
  if (MODE == 2) {
    Ah += bz * bsA;
    Al += bz * bsA;
    Bh += bz * bsB;
    Bl += bz * bsB;
    if (bias) bias += bz * bsBias;
    Cf += bz * bsC;
  }
  const int nsteps = (MODE == 1 ? kchunk : K) >> 5;
  const int wmf = (w & 1) * MF_W, wnf = (w >> 1) * NF_W;

  const short* gp[LPW];
  short* lp[LPW];
  int adv[LPW];
#pragma unroll
  for (int q = 0; q < LPW; q++) {
    int f = w * LPW + q;
    if (f < NA) {
      int p = f & 1, mf = f >> 1;
      gp[q] = (p ? Al : Ah) + (size_t)(m0 + mf * 16 + lr) * K + k0 + lg * 8;
      lp[q] = &As[p][mf][0];
      adv[q] = 32;
    } else {
      int fb = f - NA, p = fb & 1, nf = fb >> 1;
      gp[q] = (p ? Bl : Bh) + ((size_t)(n0 / 16 + nf) * kst + (k0 >> 5)) * 512 +
              lane * 8;
      lp[q] = &Bs[p][nf][0];
      adv[q] = 512;
    }
  }

  fx4 acc[MF_W][NF_W];
#pragma unroll
  for (int i = 0; i < MF_W; i++)
#pragma unroll
    for (int j = 0; j < NF_W; j++) acc[i][j] = (fx4)0.f;

  for (int s = 0; s < nsteps; s++) {
#pragma unroll
    for (int q = 0; q < LPW; q++) {
      g2l16(gp[q], lp[q]);
      gp[q] += adv[q];
    }
    __syncthreads();
    s16x8 af[MF_W][2], bf[NF_W][2];
#pragma unroll
    for (int fm = 0; fm < MF_W; fm++) {
      af[fm][0] = *(const s16x8*)&As[0][wmf + fm][lane * 8];
      af[fm][1] = *(const s16x8*)&As[1][wmf + fm][lane * 8];
    }
#pragma unroll
    for (int fn = 0; fn < NF_W; fn++) {
      bf[fn][0] = *(const s16x8*)&Bs[0][wnf + fn][lane * 8];
      bf[fn][1] = *(const s16x8*)&Bs[1][wnf + fn][lane * 8];
    }
#pragma unroll
    for (int fm = 0; fm < MF_W; fm++)
#pragma unroll
      for (int fn = 0; fn < NF_W; fn++)
        acc[fm][fn] = __builtin_amdgcn_mfma_f32_16x16x32_bf16(
            af[fm][0], bf[fn][0], acc[fm][fn], 0, 0, 0);
#pragma unroll
    for (int fm = 0; fm < MF_W; fm++)
#pragma unroll
      for (int fn = 0; fn < NF_W; fn++)
        acc[fm][fn] = __builtin_amdgcn_mfma_f32_16x16x32_bf16(
            af[fm][0], bf[fn][1], acc[fm][fn], 0, 0, 0);
#pragma unroll
    for (int fm = 0; fm < MF_W; fm++)
#pragma unroll
      for (int fn = 0; fn < NF_W; fn++)
        acc[fm][fn] = __builtin_amdgcn_mfma_f32_16x16x32_bf16(
            af[fm][1], bf[fn][0], acc[fm][fn], 0, 0, 0);
    __syncthreads();
  }

  const int orow = (lane >> 4) * 4;
  const bool rg2 = (n0 >= nsplit);
#pragma unroll
  for (int fm = 0; fm < MF_W; fm++) {
#pragma unroll
    for (int fn = 0; fn < NF_W; fn++) {
      int col = n0 + (wnf + fn) * 16 + lr;
      if (MODE == 1) {
        if (rg2) {
          int c2 = col - nsplit;
#pragma unroll
          for (int j = 0; j < 4; j++) {
            int row = m0 + (wmf + fm) * 16 + orow + j;
            C2[(size_t)row * ldc2 + c2] = acc[fm][fn][j];
          }
        } else {
#pragma unroll
          for (int j = 0; j < 4; j++) {
            int row = m0 + (wmf + fm) * 16 + orow + j;
            Cf[(size_t)row * ldc + col] = acc[fm][fn][j];
          }
        }
      } else if (rg2) {
        int c2 = col - nsplit;
#pragma unroll
        for (int j = 0; j < 4; j++) {
          int row = m0 + (wmf + fm) * 16 + orow + j;
          C2[(size_t)row * ldc2 + c2] = acc[fm][fn][j];
        }
      } else {
        float bv = bias ? bias[col] : 0.f;
#pragma unroll
        for (int j = 0; j < 4; j++) {
          int row = m0 + (wmf + fm) * 16 + orow + j;
          float v = acc[fm][fn][j] + bv;
          if (act) v = gelu_f(v);
          size_t idx = (size_t)row * ldc + col;
          if (Cf) Cf[idx] = v;
          if (Ch) {
            unsigned short hb = f2bf_u(v);
            Ch[idx] = (short)hb;
            Cl[idx] = (short)f2bf_u(v - bfu2f(hb));
          }
        }
      }
    }
  }
}

// ---------- weight packing ----------
__device__ __forceinline__ void pack_store(const float* src, short* ph,
                                           short* pl, size_t o) {
  float4 a = *(const float4*)src;
  float4 b = *(const float4*)(src + 4);
  float v[8] = {a.x, a.y, a.z, a.w, b.x, b.y, b.z, b.w};
  s16x8 hv, lv;
#pragma unroll
  for (int e = 0; e < 8; e++) {
    unsigned short h = f2bf_u(v[e]);
    hv[e] = (short)h;
    lv[e] = (short)f2bf_u(v[e] - bfu2f(h));
  }
  *(s16x8*)(ph + o) = hv;
  *(s16x8*)(pl + o) = lv;
}

// One dispatch packs all 4 per-layer weight matrices (13824 tiles).
__global__ __launch_bounds__(256) void pack_layer_k(
    const float* __restrict__ Wq, const float* __restrict__ Wk,
    const float* __restrict__ Wv, const float* __restrict__ Wao,
    const float* __restrict__ Wi, const float* __restrict__ Wo,
    short* __restrict__ qph, short* __restrict__ qpl, short* __restrict__ aph,
    short* __restrict__ apl, short* __restrict__ iph, short* __restrict__ ipl,
    short* __restrict__ oph, short* __restrict__ opl) {
  int tile = blockIdx.x * 4 + (threadIdx.x >> 6);
  int lane = threadIdx.x & 63;
  int lr = lane & 15, lg = lane >> 4;
  const float* src;
  short *ph, *pl;
  size_t o;
  if (tile < 3456) {
    int nf = tile / 24, ks = tile % 24;
    int row = nf * 16 + lr;
    const float* W = row < 768 ? Wq : row < 1536 ? Wk : Wv;
    int r = row < 768 ? row : row < 1536 ? row - 768 : row - 1536;
    src = W + (size_t)r * 768 + ks * 32 + lg * 8;
    ph = qph; pl = qpl;
    o = (size_t)tile * 512 + lane * 8;
  } else if (tile < 4608) {
    int idx = tile - 3456;
    int nf = idx / 24, ks = idx % 24;
    src = Wao + (size_t)(nf * 16 + lr) * 768 + ks * 32 + lg * 8;
    ph = aph; pl = apl;
    o = (size_t)idx * 512 + lane * 8;
  } else if (tile < 9216) {
    int idx = tile - 4608;
    int nf = idx / 24, ks = idx % 24;
    src = Wi + (size_t)(nf * 16 + lr) * 768 + ks * 32 + lg * 8;
    ph = iph; pl = ipl;
    o = (size_t)idx * 512 + lane * 8;
  } else {
    int idx = tile - 9216;
    int nf = idx / 96, ks = idx % 96;
    src = Wo + (size_t)(nf * 16 + lr) * 3072 + ks * 32 + lg * 8;
    ph = oph; pl = opl;
    o = (size_t)idx * 512 + lane * 8;
  }
  pack_store(src, ph, pl, o);
}

__global__ __launch_bounds__(256) void pack_w_k(const float* __restrict__ W,
                                                short* __restrict__ ph,
                                                short* __restrict__ pl, int K,
                                                int ntiles) {
  int tile = blockIdx.x * 4 + (threadIdx.x >> 6);
  if (tile >= ntiles) return;
  int kst = K >> 5;
  int nf = tile / kst, ks = tile - nf * kst;
  int lane = threadIdx.x & 63;
  int lr = lane & 15, lg = lane >> 4;
  const float* src = W + (size_t)(nf * 16 + lr) * K + ks * 32 + lg * 8;
  pack_store(src, ph, pl, (size_t)tile * 512 + lane * 8);
}

__global__ __launch_bounds__(256) void pack_pad_k(const float* __restrict__ W,
                                                  short* __restrict__ ph,
                                                  short* __restrict__ pl,
                                                  int K) {
  int tile = blockIdx.x * 4 + (threadIdx.x >> 6);
  int kst = K >> 5;
  if (tile >= 8 * kst) return;
  int nf = tile / kst, ks = tile - nf * kst;
  int lane = threadIdx.x & 63;
  int lr = lane & 15, lg = lane >> 4;
  int row = nf * 16 + lr;
  size_t o = (size_t)tile * 512 + lane * 8;
  if (row < 120) {
    pack_store(W + (size_t)row * K + ks * 32 + lg * 8, ph, pl, o);
  } else {
    *(s16x8*)(ph + o) = (s16x8)0;
    *(s16x8*)(pl + o) = (s16x8)0;
  }
}

__global__ __launch_bounds__(256) void concat_k(const float* __restrict__ rf,
                                                const float* __restrict__ cls,
                                                float* __restrict__ h) {
  int idx = blockIdx.x * 256 + threadIdx.x;
  if (idx >= kRows * kD) return;
  int d = idx % kD;
  int row = idx / kD;
  int s = row % kS;
  int b = row / kS;
  h[idx] = (s == 0) ? cls[d] : rf[((long)b * kSR + (s - 1)) * kD + d];
}

__global__ void cc_k(const float* __restrict__ mask, float* __restrict__ cc) {
  int d = threadIdx.x;
  if (d < kND) {
    float s = 0.f;
    for (int r = 0; r < kSR; r++) s += mask[r * kND + d];
    cc[d] = s;
  }
}

__global__ __launch_bounds__(256) void mmat_k(const float* __restrict__ Adn,
                                              const float* __restrict__ Bup,
                                              float* __restrict__ Mm) {
  int g = blockIdx.x;
  int t = threadIdx.x;
  int pair = t & 63;
  int quarter = t >> 6;
  int rp = pair >> 3, r = pair & 7;
  const float* ad = Adn + (long)(g * 8 + rp) * kH;
  const float* bu = Bup + (long)g * kH * 8 + r;
  float acc = 0.f;
  for (int hh = quarter * 768; hh < quarter * 768 + 768; hh++)
    acc += ad[hh] * bu[hh * 8];
  __shared__ float red[256];
  red[t] = acc;
  __syncthreads();
  if (t < 64) Mm[g * 64 + pair] = red[t] + red[t + 64] + red[t + 128] + red[t + 192];
}

// plain LN(x) -> hi/lo planes (layer 0 only)
__global__ __launch_bounds__(256) void ln_bf_k(const float* __restrict__ x,
                                               const float* __restrict__ g,
                                               const float* __restrict__ b,
                                               short* __restrict__ yh,
                                               short* __restrict__ yl,
                                               float eps) {
  int row = blockIdx.x;
  int t = threadIdx.x;
  long rb = (long)row * kD;
  float v0 = x[rb + t], v1 = x[rb + t + 256], v2 = x[rb + t + 512];
  float m = block_sum(v0 + v1 + v2) * (1.0f / 768.0f);
  float d0 = v0 - m, d1 = v1 - m, d2 = v2 - m;
  float q = block_sum(d0 * d0 + d1 * d1 + d2 * d2);
  float inv = rsqrtf(q * (1.0f / 768.0f) + eps);
#pragma unroll
  for (int c = 0; c < 3; c++) {
    int tt = t + c * 256;
    float dd = (c == 0 ? d0 : c == 1 ? d1 : d2);
    float val = dd * inv * g[tt] + b[tt];
    unsigned short hb = f2bf_u(val);
    yh[rb + tt] = (short)hb;
    yl[rb + tt] = (short)f2bf_u(val - bfu2f(hb));
  }
}

// odd layers: h = sum4(cwop) + bo + res1 ; n1 = LN(h) -> planes
__global__ __launch_bounds__(256) void ln_parts_k(
    const float* __restrict__ parts, const float* __restrict__ b2,
    const float* __restrict__ r2, float* __restrict__ hout,
    const float* __restrict__ g, const float* __restrict__ b,
    short* __restrict__ yh, short* __restrict__ yl, float eps) {
  int row = blockIdx.x;
  int t = threadIdx.x;
  long rb = (long)row * kD;
  float v0, v1, v2;
  {
    float s0 = 0, s1 = 0, s2 = 0;
#pragma unroll
    for (int p = 0; p < 4; p++) {
      s0 += parts[p * kPS + rb + t];
      s1 += parts[p * kPS + rb + t + 256];
      s2 += parts[p * kPS + rb + t + 512];
    }
    v0 = s0 + b2[t] + r2[rb + t];
    v1 = s1 + b2[t + 256] + r2[rb + t + 256];
    v2 = s2 + b2[t + 512] + r2[rb + t + 512];
  }
  hout[rb + t] = v0;
  hout[rb + t + 256] = v1;
  hout[rb + t + 512] = v2;
  float m = block_sum(v0 + v1 + v2) * (1.0f / 768.0f);
  float d0 = v0 - m, d1 = v1 - m, d2 = v2 - m;
  float q = block_sum(d0 * d0 + d1 * d1 + d2 * d2);
  float inv = rsqrtf(q * (1.0f / 768.0f) + eps);
#pragma unroll
  for (int c = 0; c < 3; c++) {
    int tt = t + c * 256;
    float dd = (c == 0 ? d0 : c == 1 ? d1 : d2);
    float val = dd * inv * g[tt] + b[tt];
    unsigned short hb = f2bf_u(val);
    yh[rb + tt] = (short)hb;
    yl[rb + tt] = (short)f2bf_u(val - bfu2f(hb));
  }
}

// final: out = LN(sum4(cwop) + bo + res1)
__global__ __launch_bounds__(256) void ln_row_k(
    const float* __restrict__ parts, const float* __restrict__ b2,
    const float* __restrict__ r2, const float* __restrict__ g,
    const float* __restrict__ b, float* __restrict__ y, float eps) {
  int row = blockIdx.x;
  int t = threadIdx.x;
  long rb = (long)row * kD;
  float s0 = 0, s1 = 0, s2 = 0;
#pragma unroll
  for (int p = 0; p < 4; p++) {
    s0 += parts[p * kPS + rb + t];
    s1 += parts[p * kPS + rb + t + 256];
    s2 += parts[p * kPS + rb + t + 512];
  }
  float v0 = s0 + b2[t] + r2[rb + t];
  float v1 = s1 + b2[t + 256] + r2[rb + t + 256];
  float v2 = s2 + b2[t + 512] + r2[rb + t + 512];
  float m = block_sum(v0 + v1 + v2) * (1.0f / 768.0f);
  float d0 = v0 - m, d1 = v1 - m, d2 = v2 - m;
  float q = block_sum(d0 * d0 + d1 * d1 + d2 * d2);
  float inv = rsqrtf(q * (1.0f / 768.0f) + eps);
  y[rb + t] = d0 * inv * g[t] + b[t];
  y[rb + t + 256] = d1 * inv * g[t + 256] + b[t + 256];
  y[rb + t + 512] = d2 * inv * g[t + 512] + b[t + 512];
}

// res1 = sum2(aop) + abias + h ; n2 = LN(res1) -> planes
__global__ __launch_bounds__(256) void addln_bf_k(
    const float* __restrict__ aparts, const float* __restrict__ abias,
    const float* __restrict__ hh, const float* __restrict__ g,
    const float* __restrict__ b, float* __restrict__ r1,
    short* __restrict__ n2h, short* __restrict__ n2l, float eps) {
  int row = blockIdx.x;
  int t = threadIdx.x;
  long rb = (long)row * kD;
  float v0 = aparts[rb + t] + aparts[kPS + rb + t] + abias[t] + hh[rb + t];
  float v1 = aparts[rb + t + 256] + aparts[kPS + rb + t + 256] + abias[t + 256] +
             hh[rb + t + 256];
  float v2 = aparts[rb + t + 512] + aparts[kPS + rb + t + 512] + abias[t + 512] +
             hh[rb + t + 512];
  r1[rb + t] = v0;
  r1[rb + t + 256] = v1;
  r1[rb + t + 512] = v2;
  float m = block_sum(v0 + v1 + v2) * (1.0f / 768.0f);
  float d0 = v0 - m, d1 = v1 - m, d2 = v2 - m;
  float q = block_sum(d0 * d0 + d1 * d1 + d2 * d2);
  float inv = rsqrtf(q * (1.0f / 768.0f) + eps);
#pragma unroll
  for (int c = 0; c < 3; c++) {
    int tt = t + c * 256;
    float dd = (c == 0 ? d0 : c == 1 ? d1 : d2);
    float val = dd * inv * g[tt] + b[tt];
    unsigned short hb = f2bf_u(val);
    n2h[rb + tt] = (short)hb;
    n2l[rb + tt] = (short)f2bf_u(val - bfu2f(hb));
  }
}

// One block per (b, head). Reads qkv [1920][2304], adds biases inline.
__global__ __launch_bounds__(256) void attn_k(const float* __restrict__ qkv,
                                              const float* __restrict__ bq,
                                              const float* __restrict__ bk,
                                              const float* __restrict__ bv,
                                              short* __restrict__ oh,
                                              short* __restrict__ ol) {
  int blk = blockIdx.x;
  int b = blk / kNH, hh = blk % kNH;
  __shared__ float qs[30][65], ks[30][65], vs[30][65], ps[30][32];
  int t = threadIdx.x;
  long ibase = (long)b * kS * kQKV + hh * 64;
  long obase = (long)b * kS * kD + hh * 64;
  for (int idx = t; idx < 1920; idx += 256) {
    int s = idx >> 6, d = idx & 63;
    long a = ibase + (long)s * kQKV + d;
    int bcol = hh * 64 + d;
    qs[s][d] = qkv[a] + bq[bcol];
    ks[s][d] = qkv[a + 768] + bk[bcol];
    vs[s][d] = qkv[a + 1536] + bv[bcol];
  }
  __syncthreads();
  for (int idx = t; idx < 900; idx += 256) {
    int r = idx / 30, c = idx % 30;
    float acc = 0.f;
#pragma unroll
    for (int d = 0; d < 64; d++) acc += qs[r][d] * ks[c][d];
    ps[r][c] = acc * 0.125f;
  }
  __syncthreads();
  if (t < 30) {
    float mx = -1e30f;
#pragma unroll
    for (int c = 0; c < 30; c++) mx = fmaxf(mx, ps[t][c]);
    float sm = 0.f;
#pragma unroll
    for (int c = 0; c < 30; c++) sm += expf(ps[t][c] - mx);
    float inv = 1.0f / sm;
#pragma unroll
    for (int c = 0; c < 30; c++) ps[t][c] = expf(ps[t][c] - mx) * inv;
  }
  __syncthreads();
  for (int idx = t; idx < 1920; idx += 256) {
    int r = idx >> 6, d = idx & 63;
    float acc = 0.f;
#pragma unroll
    for (int c = 0; c < 30; c++) acc += ps[r][c] * vs[c][d];
    long a = obase + (long)r * kD + d;
    unsigned short hb = f2bf_u(acc);
    oh[a] = (short)hb;
    ol[a] = (short)f2bf_u(acc - bfu2f(hb));
  }
}

// pooled (row d*64+b) = (sum_r mask*sum2(aop))/cc + bao -> hi/lo planes
__global__ __launch_bounds__(256) void pool_k(const float* __restrict__ aparts,
                                              const float* __restrict__ bao,
                                              const float* __restrict__ mask,
                                              const float* __restrict__ cc,
                                              short* __restrict__ ph,
                                              short* __restrict__ pl) {
  int blk = blockIdx.x;
  int d = blk >> 6, b = blk & 63;
  __shared__ float mr[32];
  int t = threadIdx.x;
  if (t < kSR) mr[t] = mask[t * kND + d];
  __syncthreads();
  float inv = 1.0f / cc[d];
  for (int hd = t; hd < kD; hd += 256) {
    float acc = 0.f;
    for (int r = 0; r < kSR; r++) {
      long o = ((long)b * kS + 1 + r) * kD + hd;
      acc += mr[r] * (aparts[o] + aparts[kPS + o]);
    }
    float v = acc * inv + bao[hd];
    unsigned short hb = f2bf_u(v);
    size_t o = (size_t)blk * kD + hd;
    ph[o] = (short)hb;
    pl[o] = (short)f2bf_u(v - bfu2f(hb));
  }
}

__global__ __launch_bounds__(256) void cls2_k(const float* __restrict__ z,
                                              const float* __restrict__ lng,
                                              const float* __restrict__ lnb,
                                              const float* __restrict__ w2,
                                              const float* __restrict__ b2,
                                              float* __restrict__ da) {
  int blk = blockIdx.x;
  int d = blk >> 6, b = blk & 63;
  int t = threadIdx.x;
  const float* zr = z + (long)blk * 384;
  float v0 = zr[t];
  float v1 = (t < 128) ? zr[256 + t] : 0.f;
  float m = block_sum(v0 + v1) * (1.0f / 384.0f);
  float d0 = v0 - m;
  float d1 = (t < 128) ? v1 - m : 0.f;
  float q = block_sum(d0 * d0 + d1 * d1);
  float inv = rsqrtf(q * (1.0f / 384.0f) + 1e-5f);
  const float* lg = lng + (long)d * 384;
  const float* lb = lnb + (long)d * 384;
  const float* wd = w2 + (long)d * 384;
  float p = gelu_f(d0 * inv * lg[t] + lb[t]) * wd[t];
  if (t < 128) p += gelu_f(d1 * inv * lg[256 + t] + lb[256 + t]) * wd[256 + t];
  float ps = block_sum(p);
  if (t == 0) da[b * kND + d] = (ps + b2[d] > 0.f) ? 1.f : 0.f;
}

// vv = sum4(iap) + SCALE * M_e @ u  (u single buffer from fused Wi)
__global__ __launch_bounds__(256) void vcomb_k(const float* __restrict__ ub,
                                               const float* __restrict__ iap,
                                               const float* __restrict__ Mm,
                                               float* __restrict__ vv) {
  int idx = blockIdx.x * 256 + threadIdx.x;
  if (idx >= kRows * 120) return;
  int row = idx / 120, c = idx % 120;
  int e = c >> 3, rp = c & 7;
  const float* Me = Mm + e * 64 + rp * 8;
  long rb = (long)row * 128;
  float acc = 0.f;
#pragma unroll
  for (int p = 0; p < 4; p++) acc += iap[p * kPSL + rb + c];
  const float* ur = ub + rb + e * 8;
#pragma unroll
  for (int r = 0; r < 8; r++) acc += 2.0f * Me[r] * ur[r];
  vv[rb + c] = acc;
}

// even layers: base = sum4(cwop)+bo; expert loop; h = acc+res1; then
// n1 = LN(h, ln1g/ln1b of NEXT layer) -> planes (fused).
__global__ __launch_bounds__(256) void finaleven_k(
    const float* __restrict__ parts, const float* __restrict__ bo,
    const float* __restrict__ res1, const float* __restrict__ vv,
    const float* __restrict__ Bd, const float* __restrict__ da,
    const float* __restrict__ mask, float* __restrict__ h,
    const float* __restrict__ g1, const float* __restrict__ b1,
    short* __restrict__ n1h, short* __restrict__ n1l) {
  int row = blockIdx.x;
  int b = row / kS, s = row % kS;
  int t = threadIdx.x;
  __shared__ float w[16];
  __shared__ float vvs[120];
  if (t < 120) vvs[t] = vv[(long)row * 128 + t];
  if (t < kND) w[t] = (s >= 1) ? da[b * kND + t] * mask[(s - 1) * kND + t] : 0.f;
  if (t == kND) w[kND] = 1.f;
  __syncthreads();
  float wsum = 0.f;
#pragma unroll
  for (int e = 0; e < kE; e++) wsum += w[e];
  float winv = 1.0f / wsum;
  long rb = (long)row * kD;
  float b0 = bo[t], b1v = bo[t + 256], b2v = bo[t + 512];
#pragma unroll
  for (int p = 0; p < 4; p++) {
    b0 += parts[p * kPS + rb + t];
    b1v += parts[p * kPS + rb + t + 256];
    b2v += parts[p * kPS + rb + t + 512];
  }
  float a0 = 0.f, a1 = 0.f, a2 = 0.f;
  for (int e = 0; e < kE; e++) {
    float we = w[e];
    if (we == 0.f) continue;
    const float* vr = vvs + e * 8;
    float y0 = b0 + 2.0f * dot8(Bd + ((long)(e * kD + t)) * 8, vr);
    float y1 = b1v + 2.0f * dot8(Bd + ((long)(e * kD + t + 256)) * 8, vr);
    float y2 = b2v + 2.0f * dot8(Bd + ((long)(e * kD + t + 512)) * 8, vr);
    float m = block_sum(y0 + y1 + y2) * (1.0f / 768.0f);
    float d0 = y0 - m, d1 = y1 - m, d2 = y2 - m;
    float q = block_sum(d0 * d0 + d1 * d1 + d2 * d2);
    float inv = rsqrtf(q * (1.0f / 768.0f) + 1e-5f);
    float sc = we * winv * inv;
    a0 += sc * d0;
    a1 += sc * d1;
    a2 += sc * d2;
  }
  float v0 = a0 + res1[rb + t];
  float v1 = a1 + res1[rb + t + 256];
  float v2 = a2 + res1[rb + t + 512];
  h[rb + t] = v0;
  h[rb + t + 256] = v1;
  h[rb + t + 512] = v2;
  float m = block_sum(v0 + v1 + v2) * (1.0f / 768.0f);
  float d0 = v0 - m, d1 = v1 - m, d2 = v2 - m;
  float q = block_sum(d0 * d0 + d1 * d1 + d2 * d2);
  float inv = rsqrtf(q * (1.0f / 768.0f) + 1e-12f);
#pragma unroll
  for (int c = 0; c < 3; c++) {
    int tt = t + c * 256;
    float dd = (c == 0 ? d0 : c == 1 ? d1 : d2);
    float val = dd * inv * g1[tt] + b1[tt];
    unsigned short hb = f2bf_u(val);
    n1h[rb + tt] = (short)hb;
    n1l[rb + tt] = (short)f2bf_u(val - bfu2f(hb));
  }
}

}  // namespace

extern "C" void kernel_launch(void* const* d_in, const int* in_sizes, int n_in,
                              void* d_out, int out_size, void* d_ws, size_t ws_size,
                              hipStream_t stream) {
  const float* region = (const float*)d_in[0];
  const float* mask = (const float*)d_in[1];
  const float* cls = (const float*)d_in[2];
  const float* ln1g = (const float*)d_in[3];
  const float* ln1b = (const float*)d_in[4];
  const float* ln2g = (const float*)d_in[5];
  const float* ln2b = (const float*)d_in[6];
  const float* Wq = (const float*)d_in[7];
  const float* bq = (const float*)d_in[8];
  const float* Wk = (const float*)d_in[9];
  const float* bk = (const float*)d_in[10];
  const float* Wv = (const float*)d_in[11];
  const float* bv = (const float*)d_in[12];
  const float* Wao = (const float*)d_in[13];
  const float* bao = (const float*)d_in[14];
  const float* Wi = (const float*)d_in[15];
  const float* bi = (const float*)d_in[16];
  const float* Wo = (const float*)d_in[17];
  const float* bo = (const float*)d_in[18];
  const float* fg = (const float*)d_in[19];
  const float* fb = (const float*)d_in[20];
  const float* cW1 = (const float*)d_in[21];
  const float* cb1 = (const float*)d_in[22];
  const float* clng = (const float*)d_in[23];
  const float* clnb = (const float*)d_in[24];
  const float* cW2 = (const float*)d_in[25];
  const float* cb2 = (const float*)d_in[26];
  const float* Aup = (const float*)d_in[27];
  const float* Bup = (const float*)d_in[28];
  const float* Adn = (const float*)d_in[29];
  const float* Bdn = (const float*)d_in[30];
  float* out = (float*)d_out;

  char* wsb = (char*)d_ws;
  size_t off = 0;
  auto alloc = [&](size_t bytes) {
    char* p = wsb + off;
    off = (off + bytes + 255) & ~(size_t)255;
    return (void*)p;
  };
  float* h = (float*)alloc((size_t)kRows * kD * 4);
  float* qkv = (float*)alloc((size_t)kRows * kQKV * 4);
  float* aop = (float*)alloc((size_t)2 * kRows * kD * 4);     // Wao partials
  float* res1 = (float*)alloc((size_t)kRows * kD * 4);
  float* cwop = (float*)alloc((size_t)4 * kRows * kD * 4);    // Wo partials
  float* zb = (float*)alloc((size_t)kND * kB * 384 * 4);
  float* da = (float*)alloc((size_t)kB * kND * 4);
  float* ub = (float*)alloc((size_t)kRows * 128 * 4);         // lora-up (full)
  float* iap = (float*)alloc((size_t)4 * kRows * 128 * 4);    // lora-dn parts
  float* vvb = (float*)alloc((size_t)kRows * 128 * 4);
  float* Mm = (float*)alloc((size_t)kNE * kE * 64 * 4);
  float* cc = (float*)alloc(64);
  short* n1h = (short*)alloc((size_t)kRows * kD * 2);
  short* n1l = (short*)alloc((size_t)kRows * kD * 2);
  short* n2h = (short*)alloc((size_t)kRows * kD * 2);
  short* n2l = (short*)alloc((size_t)kRows * kD * 2);
  short* inth = (short*)alloc((size_t)kRows * kH * 2);
  short* intl = (short*)alloc((size_t)kRows * kH * 2);
  short* pooledh = (short*)alloc((size_t)kND * kB * kD * 2);
  short* pooledl = (short*)alloc((size_t)kND * kB * kD * 2);
  // packed weights (frag-linear). wi/wo buffers carry lora tails (fused N).
  short* qkvph = (short*)alloc((size_t)144 * 24 * 512 * 2);
  short* qkvpl = (short*)alloc((size_t)144 * 24 * 512 * 2);
  short* waoph = (short*)alloc((size_t)48 * 24 * 512 * 2);
  short* waopl = (short*)alloc((size_t)48 * 24 * 512 * 2);
  short* wiph = (short*)alloc((size_t)200 * 24 * 512 * 2);   // 192 wi + 8 lu
  short* wipl = (short*)alloc((size_t)200 * 24 * 512 * 2);
  short* woph = (short*)alloc((size_t)56 * 96 * 512 * 2);    // 48 wo + 8 ld
  short* wopl = (short*)alloc((size_t)56 * 96 * 512 * 2);
  short* cw1ph = (short*)alloc((size_t)336 * 24 * 512 * 2);
  short* cw1pl = (short*)alloc((size_t)336 * 24 * 512 * 2);
  short* luph = wiph + (size_t)192 * 24 * 512;
  short* lupl = wipl + (size_t)192 * 24 * 512;
  short* ldph = woph + (size_t)48 * 96 * 512;
  short* ldpl = wopl + (size_t)48 * 96 * 512;

  concat_k<<<(kRows * kD + 255) / 256, 256, 0, stream>>>(region, cls, h);
  cc_k<<<1, 32, 0, stream>>>(mask, cc);
  mmat_k<<<kNE * kE, 256, 0, stream>>>(Adn, Bup, Mm);

  const int nDD = kD * kD;
  const int nDH = kD * kH;

  ln_bf_k<<<kRows, 256, 0, stream>>>(h, ln1g, ln1b, n1h, n1l, 1e-12f);

  for (int i = 0; i < kL; i++) {
    int le = i >> 1;
    bool even = (i % 2) == 0;
    pack_layer_k<<<3456, 256, 0, stream>>>(
        Wq + (long)i * nDD, Wk + (long)i * nDD, Wv + (long)i * nDD,
        Wao + (long)i * nDD, Wi + (long)i * nDH, Wo + (long)i * nDH, qkvph,
        qkvpl, waoph, waopl, wiph, wipl, woph, wopl);
    if (even) {
      pack_pad_k<<<48, 256, 0, stream>>>(Aup + (long)le * kE * 8 * kD, luph,
                                         lupl, 768);
      pack_pad_k<<<192, 256, 0, stream>>>(Adn + (long)le * kE * 8 * kH, ldph,
                                          ldpl, 3072);
      pack_w_k<<<(336 * 24) / 4, 256, 0, stream>>>(
          cW1 + (long)le * kND * 384 * kD, cw1ph, cw1pl, 768, 336 * 24);
    }

    // QKV (N=2304): 36x15 = 540 blocks
    gemm_hl<128, 64, 0><<<dim3(36, 15), 256, 0, stream>>>(
        n1h, n1l, qkvph, qkvpl, nullptr, qkv, nullptr, nullptr, nullptr, 768,
        kQKV, 0, 0, 0, kBIG, 0, 0, 0, 0, 0);
    attn_k<<<kB * kNH, 256, 0, stream>>>(qkv, bq + i * kD, bk + i * kD,
                                         bv + i * kD, n1h, n1l);
    // Wao split-K x2: 12x15x2 = 360 blocks
    gemm_hl<128, 64, 1><<<dim3(12, 15, 2), 256, 0, stream>>>(
        n1h, n1l, waoph, waopl, nullptr, aop, nullptr, nullptr, nullptr, 768,
        kD, 0, 0, 384, kBIG, 0, 0, 0, kPS, 0);
    addln_bf_k<<<kRows, 256, 0, stream>>>(aop, bao + i * kD, h, ln2g + i * kD,
                                          ln2b + i * kD, res1, n2h, n2l, 1e-12f);
    // Wi (+ fused LoRA-up on even layers): N=3200 or 3072
    gemm_hl<128, 64, 0><<<dim3(even ? 50 : 48, 15), 256, 0, stream>>>(
        n2h, n2l, wiph, wipl, bi + i * kH, nullptr, inth, intl, ub, 768, kH,
        128, 1, 0, even ? 3072 : kBIG, 0, 0, 0, 0, 0);
    // Wo (+ fused LoRA-down on even layers), split-K x4
    gemm_hl<128, 64, 1><<<dim3(even ? 14 : 12, 15, 4), 256, 0, stream>>>(
        inth, intl, woph, wopl, nullptr, cwop, nullptr, nullptr, iap, 3072, kD,
        128, 0, 768, even ? 768 : kBIG, 0, 0, 0, kPS, kPSL);
    if (even) {
      pool_k<<<kND * kB, 256, 0, stream>>>(aop, bao + i * kD, mask, cc, pooledh,
                                           pooledl);
      // batched classifier GEMM: per disease d, M=64, N=384, K=768
      gemm_hl<64, 64, 2><<<dim3(6, 1, 14), 256, 0, stream>>>(
          pooledh, pooledl, cw1ph, cw1pl, cb1 + (long)le * kND * 384, zb,
          nullptr, nullptr, nullptr, 768, 384, 0, 0, 0, kBIG, (long)64 * kD,
          (long)576 * 512, 384, (long)64 * 384, 0);
      cls2_k<<<kND * kB, 256, 0, stream>>>(zb, clng + (long)le * kND * 384,
                                           clnb + (long)le * kND * 384,
                                           cW2 + (long)le * kND * 384,
                                           cb2 + le * kND, da);
      vcomb_k<<<(kRows * 120 + 255) / 256, 256, 0, stream>>>(
          ub, iap, Mm + le * kE * 64, vvb);
      finaleven_k<<<kRows, 256, 0, stream>>>(
          cwop, bo + i * kD, res1, vvb, Bdn + (long)le * kE * kD * 8, da, mask,
          h, ln1g + (i + 1) * kD, ln1b + (i + 1) * kD, n1h, n1l);
    } else if (i < kL - 1) {
      ln_parts_k<<<kRows, 256, 0, stream>>>(cwop, bo + i * kD, res1, h,
                                            ln1g + (i + 1) * kD,
                                            ln1b + (i + 1) * kD, n1h, n1l,
                                            1e-12f);
    } else {
      ln_row_k<<<kRows, 256, 0, stream>>>(cwop, bo + i * kD, res1, fg, fb, out,
                                          1e-12f);
    }
  }
}

// Round 12
// 3067.560 us; speedup vs baseline: 1.0363x; 1.0363x over previous
//
#include <hip/hip_runtime.h>

namespace {

constexpr int kB = 64, kSR = 29, kS = 30, kD = 768, kH = 3072, kL = 12;
constexpr int kNH = 12, kND = 14, kE = 15, kNE = 6;
constexpr int kRows = kB * kS;  // 1920
constexpr int kQKV = 2304;
constexpr long kPS = (long)kRows * kD;    // partial stride (fp32 elems)
constexpr long kPSL = (long)kRows * 128;  // lora partial stride
constexpr int kBIG = 1 << 30;

typedef __attribute__((ext_vector_type(8))) short s16x8;
typedef __attribute__((ext_vector_type(4))) float fx4;

__device__ __forceinline__ float gelu_f(float x) {
  return 0.5f * x * (1.0f + erff(x * 0.70710678118654752f));
}

__device__ __forceinline__ unsigned short f2bf_u(float x) {
  union { float f; unsigned u; } v;
  v.f = x;
  unsigned r = v.u + 0x7fffu + ((v.u >> 16) & 1u);
  return (unsigned short)(r >> 16);
}
__device__ __forceinline__ float bfu2f(unsigned short h) {
  union { unsigned u; float f; } v;
  v.u = ((unsigned)h) << 16;
  return v.f;
}

__device__ __forceinline__ void g2l16(const short* g, short* l) {
  __builtin_amdgcn_global_load_lds(
      (const __attribute__((address_space(1))) unsigned int*)g,
      (__attribute__((address_space(3))) unsigned int*)l, 16, 0, 0);
}

// XCD-aware bijective block swizzle (8 XCDs).
__device__ __forceinline__ void swz_block(int& bx, int& by, int& bz) {
  int gx = gridDim.x, gy = gridDim.y;
  int nwg = gx * gy * (int)gridDim.z;
  int orig = blockIdx.x + gx * (blockIdx.y + gy * blockIdx.z);
  int q = nwg >> 3, r = nwg & 7;
  int xcd = orig & 7, idx = orig >> 3;
  int s = (xcd < r ? xcd * (q + 1) : r * (q + 1) + (xcd - r) * q) + idx;
  bx = s % gx;
  int t2 = s / gx;
  by = t2 % gy;
  bz = t2 / gy;
}

__device__ __forceinline__ float block_sum(float v) {
  __shared__ float sb[4];
#pragma unroll
  for (int o = 32; o > 0; o >>= 1) v += __shfl_down(v, o, 64);
  int w = threadIdx.x >> 6;
  __syncthreads();
  if ((threadIdx.x & 63) == 0) sb[w] = v;
  __syncthreads();
  return sb[0] + sb[1] + sb[2] + sb[3];
}

__device__ __forceinline__ float dot8(const float* __restrict__ p,
                                      const float* __restrict__ q) {
  float4 x = *(const float4*)p;
  float4 y = *(const float4*)(p + 4);
  return x.x * q[0] + x.y * q[1] + x.z * q[2] + x.w * q[3] +
         y.x * q[4] + y.y * q[5] + y.z * q[6] + y.w * q[7];
}

// ---------------------------------------------------------------------------
// MFMA GEMM, C = A @ B^T, hi/lo bf16 planes, 3-pass (hh+hl+lh ~ fp32).
// A: row-major [M][K] planes. B: PRE-PACKED fragment-linear planes.
// Tile BMxBN (64x64 default: 16KB LDS single-buffer, grids 4-6 blocks/CU so
// TLP across co-resident blocks hides the stage drain - m114).
// 4 waves (2x2). m97-style loop: stage -> sync -> MFMA -> sync.
// FUSED-N: columns >= nsplit route to C2 (fp32, ldc2), no bias/act.
// MODE: 0 plain, 1 split-K partial buffers, 2 batched over bz.
// ---------------------------------------------------------------------------
template <int BM, int BN, int MODE>
__global__ __launch_bounds__(256) void gemm_hl(
    const short* __restrict__ Ah, const short* __restrict__ Al,
    const short* __restrict__ Bh, const short* __restrict__ Bl,
    const float* __restrict__ bias, float* __restrict__ Cf,
    short* __restrict__ Ch, short* __restrict__ Cl, float* __restrict__ C2,
    int K, int ldc, int ldc2, int act, int kchunk, int nsplit, long bsA,
    long bsB, long bsBias, long bsC, long bsC2) {
  constexpr int MFR = BM / 16, NFR = BN / 16;
  constexpr int NA = 2 * MFR, NB = 2 * NFR, LPW = (NA + NB) / 4;
  constexpr int MF_W = MFR / 2, NF_W = NFR / 2;
  __shared__ __align__(16) short As[2][MFR][512];
  __shared__ __align__(16) short Bs[2][NFR][512];
  int bx, by, bz;
  swz_block(bx, by, bz);
  const int t = threadIdx.x, w = t >> 6, lane = t & 63;
  const int lr = lane & 15, lg = lane >> 4;
  const int m0 = by * BM, n0 = bx * BN;
  const int kst = K >> 5;
  int k0 = 0;
  if (MODE == 1) {
    k0 = bz * kchunk;
    Cf += bz * bsC;
    C2 += bz * bsC2;
  }
  if (MODE == 2) {
    Ah += bz * bsA;
    Al += bz * bsA;
    Bh += bz * bsB;
    Bl += bz * bsB;
    if (bias) bias += bz * bsBias;
    Cf += bz * bsC;
  }
  const int nsteps = (MODE == 1 ? kchunk : K) >> 5;
  const int wmf = (w & 1) * MF_W, wnf = (w >> 1) * NF_W;

  const short* gp[LPW];
  short* lp[LPW];
  int adv[LPW];
#pragma unroll
  for (int q = 0; q < LPW; q++) {
    int f = w * LPW + q;
    if (f < NA) {
      int p = f & 1, mf = f >> 1;
      gp[q] = (p ? Al : Ah) + (size_t)(m0 + mf * 16 + lr) * K + k0 + lg * 8;
      lp[q] = &As[p][mf][0];
      adv[q] = 32;
    } else {
      int fb = f - NA, p = fb & 1, nf = fb >> 1;
      gp[q] = (p ? Bl : Bh) + ((size_t)(n0 / 16 + nf) * kst + (k0 >> 5)) * 512 +
              lane * 8;
      lp[q] = &Bs[p][nf][0];
      adv[q] = 512;
    }
  }

  fx4 acc[MF_W][NF_W];
#pragma unroll
  for (int i = 0; i < MF_W; i++)
#pragma unroll
    for (int j = 0; j < NF_W; j++) acc[i][j] = (fx4)0.f;

  for (int s = 0; s < nsteps; s++) {
#pragma unroll
    for (int q = 0; q < LPW; q++) {
      g2l16(gp[q], lp[q]);
      gp[q] += adv[q];
    }
    __syncthreads();
    s16x8 af[MF_W][2], bf[NF_W][2];
#pragma unroll
    for (int fm = 0; fm < MF_W; fm++) {
      af[fm][0] = *(const s16x8*)&As[0][wmf + fm][lane * 8];
      af[fm][1] = *(const s16x8*)&As[1][wmf + fm][lane * 8];
    }
#pragma unroll
    for (int fn = 0; fn < NF_W; fn++) {
      bf[fn][0] = *(const s16x8*)&Bs[0][wnf + fn][lane * 8];
      bf[fn][1] = *(const s16x8*)&Bs[1][wnf + fn][lane * 8];
    }
#pragma unroll
    for (int fm = 0; fm < MF_W; fm++)
#pragma unroll
      for (int fn = 0; fn < NF_W; fn++)
        acc[fm][fn] = __builtin_amdgcn_mfma_f32_16x16x32_bf16(
            af[fm][0], bf[fn][0], acc[fm][fn], 0, 0, 0);
#pragma unroll
    for (int fm = 0; fm < MF_W; fm++)
#pragma unroll
      for (int fn = 0; fn < NF_W; fn++)
        acc[fm][fn] = __builtin_amdgcn_mfma_f32_16x16x32_bf16(
            af[fm][0], bf[fn][1], acc[fm][fn], 0, 0, 0);
#pragma unroll
    for (int fm = 0; fm < MF_W; fm++)
#pragma unroll
      for (int fn = 0; fn < NF_W; fn++)
        acc[fm][fn] = __builtin_amdgcn_mfma_f32_16x16x32_bf16(
            af[fm][1], bf[fn][0], acc[fm][fn], 0, 0, 0);
    __syncthreads();
  }

  const int orow = (lane >> 4) * 4;
  const bool rg2 = (n0 >= nsplit);
#pragma unroll
  for (int fm = 0; fm < MF_W; fm++) {
#pragma unroll
    for (int fn = 0; fn < NF_W; fn++) {
      int col = n0 + (wnf + fn) * 16 + lr;
      if (MODE == 1) {
        if (rg2) {
          int c2 = col - nsplit;
#pragma unroll
          for (int j = 0; j < 4; j++) {
            int row = m0 + (wmf + fm) * 16 + orow + j;
            C2[(size_t)row * ldc2 + c2] = acc[fm][fn][j];
          }
        } else {
#pragma unroll
          for (int j = 0; j < 4; j++) {
            int row = m0 + (wmf + fm) * 16 + orow + j;
            Cf[(size_t)row * ldc + col] = acc[fm][fn][j];
          }
        }
      } else if (rg2) {
        int c2 = col - nsplit;
#pragma unroll
        for (int j = 0; j < 4; j++) {
          int row = m0 + (wmf + fm) * 16 + orow + j;
          C2[(size_t)row * ldc2 + c2] = acc[fm][fn][j];
        }
      } else {
        float bv = bias ? bias[col] : 0.f;
#pragma unroll
        for (int j = 0; j < 4; j++) {
          int row = m0 + (wmf + fm) * 16 + orow + j;
          float v = acc[fm][fn][j] + bv;
          if (act) v = gelu_f(v);
          size_t idx = (size_t)row * ldc + col;
          if (Cf) Cf[idx] = v;
          if (Ch) {
            unsigned short hb = f2bf_u(v);
            Ch[idx] = (short)hb;
            Cl[idx] = (short)f2bf_u(v - bfu2f(hb));
          }
        }
      }
    }
  }
}

// ---------- weight packing ----------
__device__ __forceinline__ void pack_store(const float* src, short* ph,
                                           short* pl, size_t o) {
  float4 a = *(const float4*)src;
  float4 b = *(const float4*)(src + 4);
  float v[8] = {a.x, a.y, a.z, a.w, b.x, b.y, b.z, b.w};
  s16x8 hv, lv;
#pragma unroll
  for (int e = 0; e < 8; e++) {
    unsigned short h = f2bf_u(v[e]);
    hv[e] = (short)h;
    lv[e] = (short)f2bf_u(v[e] - bfu2f(h));
  }
  *(s16x8*)(ph + o) = hv;
  *(s16x8*)(pl + o) = lv;
}

// One dispatch packs all 4 per-layer weight matrices (13824 tiles).
__global__ __launch_bounds__(256) void pack_layer_k(
    const float* __restrict__ Wq, const float* __restrict__ Wk,
    const float* __restrict__ Wv, const float* __restrict__ Wao,
    const float* __restrict__ Wi, const float* __restrict__ Wo,
    short* __restrict__ qph, short* __restrict__ qpl, short* __restrict__ aph,
    short* __restrict__ apl, short* __restrict__ iph, short* __restrict__ ipl,
    short* __restrict__ oph, short* __restrict__ opl) {
  int tile = blockIdx.x * 4 + (threadIdx.x >> 6);
  int lane = threadIdx.x & 63;
  int lr = lane & 15, lg = lane >> 4;
  const float* src;
  short *ph, *pl;
  size_t o;
  if (tile < 3456) {
    int nf = tile / 24, ks = tile % 24;
    int row = nf * 16 + lr;
    const float* W = row < 768 ? Wq : row < 1536 ? Wk : Wv;
    int r = row < 768 ? row : row < 1536 ? row - 768 : row - 1536;
    src = W + (size_t)r * 768 + ks * 32 + lg * 8;
    ph = qph; pl = qpl;
    o = (size_t)tile * 512 + lane * 8;
  } else if (tile < 4608) {
    int idx = tile - 3456;
    int nf = idx / 24, ks = idx % 24;
    src = Wao + (size_t)(nf * 16 + lr) * 768 + ks * 32 + lg * 8;
    ph = aph; pl = apl;
    o = (size_t)idx * 512 + lane * 8;
  } else if (tile < 9216) {
    int idx = tile - 4608;
    int nf = idx / 24, ks = idx % 24;
    src = Wi + (size_t)(nf * 16 + lr) * 768 + ks * 32 + lg * 8;
    ph = iph; pl = ipl;
    o = (size_t)idx * 512 + lane * 8;
  } else {
    int idx = tile - 9216;
    int nf = idx / 96, ks = idx % 96;
    src = Wo + (size_t)(nf * 16 + lr) * 3072 + ks * 32 + lg * 8;
    ph = oph; pl = opl;
    o = (size_t)idx * 512 + lane * 8;
  }
  pack_store(src, ph, pl, o);
}

__global__ __launch_bounds__(256) void pack_w_k(const float* __restrict__ W,
                                                short* __restrict__ ph,
                                                short* __restrict__ pl, int K,
                                                int ntiles) {
  int tile = blockIdx.x * 4 + (threadIdx.x >> 6);
  if (tile >= ntiles) return;
  int kst = K >> 5;
  int nf = tile / kst, ks = tile - nf * kst;
  int lane = threadIdx.x & 63;
  int lr = lane & 15, lg = lane >> 4;
  const float* src = W + (size_t)(nf * 16 + lr) * K + ks * 32 + lg * 8;
  pack_store(src, ph, pl, (size_t)tile * 512 + lane * 8);
}

__global__ __launch_bounds__(256) void pack_pad_k(const float* __restrict__ W,
                                                  short* __restrict__ ph,
                                                  short* __restrict__ pl,
                                                  int K) {
  int tile = blockIdx.x * 4 + (threadIdx.x >> 6);
  int kst = K >> 5;
  if (tile >= 8 * kst) return;
  int nf = tile / kst, ks = tile - nf * kst;
  int lane = threadIdx.x & 63;
  int lr = lane & 15, lg = lane >> 4;
  int row = nf * 16 + lr;
  size_t o = (size_t)tile * 512 + lane * 8;
  if (row < 120) {
    pack_store(W + (size_t)row * K + ks * 32 + lg * 8, ph, pl, o);
  } else {
    *(s16x8*)(ph + o) = (s16x8)0;
    *(s16x8*)(pl + o) = (s16x8)0;
  }
}

__global__ __launch_bounds__(256) void concat_k(const float* __restrict__ rf,
                                                const float* __restrict__ cls,
                                                float* __restrict__ h) {
  int idx = blockIdx.x * 256 + threadIdx.x;
  if (idx >= kRows * kD) return;
  int d = idx % kD;
  int row = idx / kD;
  int s = row % kS;
  int b = row / kS;
  h[idx] = (s == 0) ? cls[d] : rf[((long)b * kSR + (s - 1)) * kD + d];
}

__global__ void cc_k(const float* __restrict__ mask, float* __restrict__ cc) {
  int d = threadIdx.x;
  if (d < kND) {
    float s = 0.f;
    for (int r = 0; r < kSR; r++) s += mask[r * kND + d];
    cc[d] = s;
  }
}

__global__ __launch_bounds__(256) void mmat_k(const float* __restrict__ Adn,
                                              const float* __restrict__ Bup,
                                              float* __restrict__ Mm) {
  int g = blockIdx.x;
  int t = threadIdx.x;
  int pair = t & 63;
  int quarter = t >> 6;
  int rp = pair >> 3, r = pair & 7;
  const float* ad = Adn + (long)(g * 8 + rp) * kH;
  const float* bu = Bup + (long)g * kH * 8 + r;
  float acc = 0.f;
  for (int hh = quarter * 768; hh < quarter * 768 + 768; hh++)
    acc += ad[hh] * bu[hh * 8];
  __shared__ float red[256];
  red[t] = acc;
  __syncthreads();
  if (t < 64) Mm[g * 64 + pair] = red[t] + red[t + 64] + red[t + 128] + red[t + 192];
}

// plain LN(x) -> hi/lo planes (layer 0 only)
__global__ __launch_bounds__(256) void ln_bf_k(const float* __restrict__ x,
                                               const float* __restrict__ g,
                                               const float* __restrict__ b,
                                               short* __restrict__ yh,
                                               short* __restrict__ yl,
                                               float eps) {
  int row = blockIdx.x;
  int t = threadIdx.x;
  long rb = (long)row * kD;
  float v0 = x[rb + t], v1 = x[rb + t + 256], v2 = x[rb + t + 512];
  float m = block_sum(v0 + v1 + v2) * (1.0f / 768.0f);
  float d0 = v0 - m, d1 = v1 - m, d2 = v2 - m;
  float q = block_sum(d0 * d0 + d1 * d1 + d2 * d2);
  float inv = rsqrtf(q * (1.0f / 768.0f) + eps);
#pragma unroll
  for (int c = 0; c < 3; c++) {
    int tt = t + c * 256;
    float dd = (c == 0 ? d0 : c == 1 ? d1 : d2);
    float val = dd * inv * g[tt] + b[tt];
    unsigned short hb = f2bf_u(val);
    yh[rb + tt] = (short)hb;
    yl[rb + tt] = (short)f2bf_u(val - bfu2f(hb));
  }
}

// odd layers: h = sum4(cwop) + bo + res1 ; n1 = LN(h) -> planes
__global__ __launch_bounds__(256) void ln_parts_k(
    const float* __restrict__ parts, const float* __restrict__ b2,
    const float* __restrict__ r2, float* __restrict__ hout,
    const float* __restrict__ g, const float* __restrict__ b,
    short* __restrict__ yh, short* __restrict__ yl, float eps) {
  int row = blockIdx.x;
  int t = threadIdx.x;
  long rb = (long)row * kD;
  float v0, v1, v2;
  {
    float s0 = 0, s1 = 0, s2 = 0;
#pragma unroll
    for (int p = 0; p < 4; p++) {
      s0 += parts[p * kPS + rb + t];
      s1 += parts[p * kPS + rb + t + 256];
      s2 += parts[p * kPS + rb + t + 512];
    }
    v0 = s0 + b2[t] + r2[rb + t];
    v1 = s1 + b2[t + 256] + r2[rb + t + 256];
    v2 = s2 + b2[t + 512] + r2[rb + t + 512];
  }
  hout[rb + t] = v0;
  hout[rb + t + 256] = v1;
  hout[rb + t + 512] = v2;
  float m = block_sum(v0 + v1 + v2) * (1.0f / 768.0f);
  float d0 = v0 - m, d1 = v1 - m, d2 = v2 - m;
  float q = block_sum(d0 * d0 + d1 * d1 + d2 * d2);
  float inv = rsqrtf(q * (1.0f / 768.0f) + eps);
#pragma unroll
  for (int c = 0; c < 3; c++) {
    int tt = t + c * 256;
    float dd = (c == 0 ? d0 : c == 1 ? d1 : d2);
    float val = dd * inv * g[tt] + b[tt];
    unsigned short hb = f2bf_u(val);
    yh[rb + tt] = (short)hb;
    yl[rb + tt] = (short)f2bf_u(val - bfu2f(hb));
  }
}

// final: out = LN(sum4(cwop) + bo + res1)
__global__ __launch_bounds__(256) void ln_row_k(
    const float* __restrict__ parts, const float* __restrict__ b2,
    const float* __restrict__ r2, const float* __restrict__ g,
    const float* __restrict__ b, float* __restrict__ y, float eps) {
  int row = blockIdx.x;
  int t = threadIdx.x;
  long rb = (long)row * kD;
  float s0 = 0, s1 = 0, s2 = 0;
#pragma unroll
  for (int p = 0; p < 4; p++) {
    s0 += parts[p * kPS + rb + t];
    s1 += parts[p * kPS + rb + t + 256];
    s2 += parts[p * kPS + rb + t + 512];
  }
  float v0 = s0 + b2[t] + r2[rb + t];
  float v1 = s1 + b2[t + 256] + r2[rb + t + 256];
  float v2 = s2 + b2[t + 512] + r2[rb + t + 512];
  float m = block_sum(v0 + v1 + v2) * (1.0f / 768.0f);
  float d0 = v0 - m, d1 = v1 - m, d2 = v2 - m;
  float q = block_sum(d0 * d0 + d1 * d1 + d2 * d2);
  float inv = rsqrtf(q * (1.0f / 768.0f) + eps);
  y[rb + t] = d0 * inv * g[t] + b[t];
  y[rb + t + 256] = d1 * inv * g[t + 256] + b[t + 256];
  y[rb + t + 512] = d2 * inv * g[t + 512] + b[t + 512];
}

// res1 = sum2(aop) + abias + h ; n2 = LN(res1) -> planes
__global__ __launch_bounds__(256) void addln_bf_k(
    const float* __restrict__ aparts, const float* __restrict__ abias,
    const float* __restrict__ hh, const float* __restrict__ g,
    const float* __restrict__ b, float* __restrict__ r1,
    short* __restrict__ n2h, short* __restrict__ n2l, float eps) {
  int row = blockIdx.x;
  int t = threadIdx.x;
  long rb = (long)row * kD;
  float v0 = aparts[rb + t] + aparts[kPS + rb + t] + abias[t] + hh[rb + t];
  float v1 = aparts[rb + t + 256] + aparts[kPS + rb + t + 256] + abias[t + 256] +
             hh[rb + t + 256];
  float v2 = aparts[rb + t + 512] + aparts[kPS + rb + t + 512] + abias[t + 512] +
             hh[rb + t + 512];
  r1[rb + t] = v0;
  r1[rb + t + 256] = v1;
  r1[rb + t + 512] = v2;
  float m = block_sum(v0 + v1 + v2) * (1.0f / 768.0f);
  float d0 = v0 - m, d1 = v1 - m, d2 = v2 - m;
  float q = block_sum(d0 * d0 + d1 * d1 + d2 * d2);
  float inv = rsqrtf(q * (1.0f / 768.0f) + eps);
#pragma unroll
  for (int c = 0; c < 3; c++) {
    int tt = t + c * 256;
    float dd = (c == 0 ? d0 : c == 1 ? d1 : d2);
    float val = dd * inv * g[tt] + b[tt];
    unsigned short hb = f2bf_u(val);
    n2h[rb + tt] = (short)hb;
    n2l[rb + tt] = (short)f2bf_u(val - bfu2f(hb));
  }
}

// One block per (b, head). Reads qkv [1920][2304], adds biases inline.
__global__ __launch_bounds__(256) void attn_k(const float* __restrict__ qkv,
                                              const float* __restrict__ bq,
                                              const float* __restrict__ bk,
                                              const float* __restrict__ bv,
                                              short* __restrict__ oh,
                                              short* __restrict__ ol) {
  int blk = blockIdx.x;
  int b = blk / kNH, hh = blk % kNH;
  __shared__ float qs[30][65], ks[30][65], vs[30][65], ps[30][32];
  int t = threadIdx.x;
  long ibase = (long)b * kS * kQKV + hh * 64;
  long obase = (long)b * kS * kD + hh * 64;
  for (int idx = t; idx < 1920; idx += 256) {
    int s = idx >> 6, d = idx & 63;
    long a = ibase + (long)s * kQKV + d;
    int bcol = hh * 64 + d;
    qs[s][d] = qkv[a] + bq[bcol];
    ks[s][d] = qkv[a + 768] + bk[bcol];
    vs[s][d] = qkv[a + 1536] + bv[bcol];
  }
  __syncthreads();
  for (int idx = t; idx < 900; idx += 256) {
    int r = idx / 30, c = idx % 30;
    float acc = 0.f;
#pragma unroll
    for (int d = 0; d < 64; d++) acc += qs[r][d] * ks[c][d];
    ps[r][c] = acc * 0.125f;
  }
  __syncthreads();
  if (t < 30) {
    float mx = -1e30f;
#pragma unroll
    for (int c = 0; c < 30; c++) mx = fmaxf(mx, ps[t][c]);
    float sm = 0.f;
#pragma unroll
    for (int c = 0; c < 30; c++) sm += expf(ps[t][c] - mx);
    float inv = 1.0f / sm;
#pragma unroll
    for (int c = 0; c < 30; c++) ps[t][c] = expf(ps[t][c] - mx) * inv;
  }
  __syncthreads();
  for (int idx = t; idx < 1920; idx += 256) {
    int r = idx >> 6, d = idx & 63;
    float acc = 0.f;
#pragma unroll
    for (int c = 0; c < 30; c++) acc += ps[r][c] * vs[c][d];
    long a = obase + (long)r * kD + d;
    unsigned short hb = f2bf_u(acc);
    oh[a] = (short)hb;
    ol[a] = (short)f2bf_u(acc - bfu2f(hb));
  }
}

// pooled (row d*64+b) = (sum_r mask*sum2(aop))/cc + bao -> hi/lo planes
__global__ __launch_bounds__(256) void pool_k(const float* __restrict__ aparts,
                                              const float* __restrict__ bao,
                                              const float* __restrict__ mask,
                                              const float* __restrict__ cc,
                                              short* __restrict__ ph,
                                              short* __restrict__ pl) {
  int blk = blockIdx.x;
  int d = blk >> 6, b = blk & 63;
  __shared__ float mr[32];
  int t = threadIdx.x;
  if (t < kSR) mr[t] = mask[t * kND + d];
  __syncthreads();
  float inv = 1.0f / cc[d];
  for (int hd = t; hd < kD; hd += 256) {
    float acc = 0.f;
    for (int r = 0; r < kSR; r++) {
      long o = ((long)b * kS + 1 + r) * kD + hd;
      acc += mr[r] * (aparts[o] + aparts[kPS + o]);
    }
    float v = acc * inv + bao[hd];
    unsigned short hb = f2bf_u(v);
    size_t o = (size_t)blk * kD + hd;
    ph[o] = (short)hb;
    pl[o] = (short)f2bf_u(v - bfu2f(hb));
  }
}

__global__ __launch_bounds__(256) void cls2_k(const float* __restrict__ z,
                                              const float* __restrict__ lng,
                                              const float* __restrict__ lnb,
                                              const float* __restrict__ w2,
                                              const float* __restrict__ b2,
                                              float* __restrict__ da) {
  int blk = blockIdx.x;
  int d = blk >> 6, b = blk & 63;
  int t = threadIdx.x;
  const float* zr = z + (long)blk * 384;
  float v0 = zr[t];
  float v1 = (t < 128) ? zr[256 + t] : 0.f;
  float m = block_sum(v0 + v1) * (1.0f / 384.0f);
  float d0 = v0 - m;
  float d1 = (t < 128) ? v1 - m : 0.f;
  float q = block_sum(d0 * d0 + d1 * d1);
  float inv = rsqrtf(q * (1.0f / 384.0f) + 1e-5f);
  const float* lg = lng + (long)d * 384;
  const float* lb = lnb + (long)d * 384;
  const float* wd = w2 + (long)d * 384;
  float p = gelu_f(d0 * inv * lg[t] + lb[t]) * wd[t];
  if (t < 128) p += gelu_f(d1 * inv * lg[256 + t] + lb[256 + t]) * wd[256 + t];
  float ps = block_sum(p);
  if (t == 0) da[b * kND + d] = (ps + b2[d] > 0.f) ? 1.f : 0.f;
}

// vv = sum4(iap) + SCALE * M_e @ u  (u single buffer from fused Wi)
__global__ __launch_bounds__(256) void vcomb_k(const float* __restrict__ ub,
                                               const float* __restrict__ iap,
                                               const float* __restrict__ Mm,
                                               float* __restrict__ vv) {
  int idx = blockIdx.x * 256 + threadIdx.x;
  if (idx >= kRows * 120) return;
  int row = idx / 120, c = idx % 120;
  int e = c >> 3, rp = c & 7;
  const float* Me = Mm + e * 64 + rp * 8;
  long rb = (long)row * 128;
  float acc = 0.f;
#pragma unroll
  for (int p = 0; p < 4; p++) acc += iap[p * kPSL + rb + c];
  const float* ur = ub + rb + e * 8;
#pragma unroll
  for (int r = 0; r < 8; r++) acc += 2.0f * Me[r] * ur[r];
  vv[rb + c] = acc;
}

// even layers: base = sum4(cwop)+bo; expert loop; h = acc+res1; then
// n1 = LN(h, ln1g/ln1b of NEXT layer) -> planes (fused).
__global__ __launch_bounds__(256) void finaleven_k(
    const float* __restrict__ parts, const float* __restrict__ bo,
    const float* __restrict__ res1, const float* __restrict__ vv,
    const float* __restrict__ Bd, const float* __restrict__ da,
    const float* __restrict__ mask, float* __restrict__ h,
    const float* __restrict__ g1, const float* __restrict__ b1,
    short* __restrict__ n1h, short* __restrict__ n1l) {
  int row = blockIdx.x;
  int b = row / kS, s = row % kS;
  int t = threadIdx.x;
  __shared__ float w[16];
  __shared__ float vvs[120];
  if (t < 120) vvs[t] = vv[(long)row * 128 + t];
  if (t < kND) w[t] = (s >= 1) ? da[b * kND + t] * mask[(s - 1) * kND + t] : 0.f;
  if (t == kND) w[kND] = 1.f;
  __syncthreads();
  float wsum = 0.f;
#pragma unroll
  for (int e = 0; e < kE; e++) wsum += w[e];
  float winv = 1.0f / wsum;
  long rb = (long)row * kD;
  float b0 = bo[t], b1v = bo[t + 256], b2v = bo[t + 512];
#pragma unroll
  for (int p = 0; p < 4; p++) {
    b0 += parts[p * kPS + rb + t];
    b1v += parts[p * kPS + rb + t + 256];
    b2v += parts[p * kPS + rb + t + 512];
  }
  float a0 = 0.f, a1 = 0.f, a2 = 0.f;
  for (int e = 0; e < kE; e++) {
    float we = w[e];
    if (we == 0.f) continue;
    const float* vr = vvs + e * 8;
    float y0 = b0 + 2.0f * dot8(Bd + ((long)(e * kD + t)) * 8, vr);
    float y1 = b1v + 2.0f * dot8(Bd + ((long)(e * kD + t + 256)) * 8, vr);
    float y2 = b2v + 2.0f * dot8(Bd + ((long)(e * kD + t + 512)) * 8, vr);
    float m = block_sum(y0 + y1 + y2) * (1.0f / 768.0f);
    float d0 = y0 - m, d1 = y1 - m, d2 = y2 - m;
    float q = block_sum(d0 * d0 + d1 * d1 + d2 * d2);
    float inv = rsqrtf(q * (1.0f / 768.0f) + 1e-5f);
    float sc = we * winv * inv;
    a0 += sc * d0;
    a1 += sc * d1;
    a2 += sc * d2;
  }
  float v0 = a0 + res1[rb + t];
  float v1 = a1 + res1[rb + t + 256];
  float v2 = a2 + res1[rb + t + 512];
  h[rb + t] = v0;
  h[rb + t + 256] = v1;
  h[rb + t + 512] = v2;
  float m = block_sum(v0 + v1 + v2) * (1.0f / 768.0f);
  float d0 = v0 - m, d1 = v1 - m, d2 = v2 - m;
  float q = block_sum(d0 * d0 + d1 * d1 + d2 * d2);
  float inv = rsqrtf(q * (1.0f / 768.0f) + 1e-12f);
#pragma unroll
  for (int c = 0; c < 3; c++) {
    int tt = t + c * 256;
    float dd = (c == 0 ? d0 : c == 1 ? d1 : d2);
    float val = dd * inv * g1[tt] + b1[tt];
    unsigned short hb = f2bf_u(val);
    n1h[rb + tt] = (short)hb;
    n1l[rb + tt] = (short)f2bf_u(val - bfu2f(hb));
  }
}

}  // namespace

extern "C" void kernel_launch(void* const* d_in, const int* in_sizes, int n_in,
                              void* d_out, int out_size, void* d_ws, size_t ws_size,
                              hipStream_t stream) {
  const float* region = (const float*)d_in[0];
  const float* mask = (const float*)d_in[1];
  const float* cls = (const float*)d_in[2];
  const float* ln1g = (const float*)d_in[3];
  const float* ln1b = (const float*)d_in[4];
  const float* ln2g = (const float*)d_in[5];
  const float* ln2b = (const float*)d_in[6];
  const float* Wq = (const float*)d_in[7];
  const float* bq = (const float*)d_in[8];
  const float* Wk = (const float*)d_in[9];
  const float* bk = (const float*)d_in[10];
  const float* Wv = (const float*)d_in[11];
  const float* bv = (const float*)d_in[12];
  const float* Wao = (const float*)d_in[13];
  const float* bao = (const float*)d_in[14];
  const float* Wi = (const float*)d_in[15];
  const float* bi = (const float*)d_in[16];
  const float* Wo = (const float*)d_in[17];
  const float* bo = (const float*)d_in[18];
  const float* fg = (const float*)d_in[19];
  const float* fb = (const float*)d_in[20];
  const float* cW1 = (const float*)d_in[21];
  const float* cb1 = (const float*)d_in[22];
  const float* clng = (const float*)d_in[23];
  const float* clnb = (const float*)d_in[24];
  const float* cW2 = (const float*)d_in[25];
  const float* cb2 = (const float*)d_in[26];
  const float* Aup = (const float*)d_in[27];
  const float* Bup = (const float*)d_in[28];
  const float* Adn = (const float*)d_in[29];
  const float* Bdn = (const float*)d_in[30];
  float* out = (float*)d_out;

  char* wsb = (char*)d_ws;
  size_t off = 0;
  auto alloc = [&](size_t bytes) {
    char* p = wsb + off;
    off = (off + bytes + 255) & ~(size_t)255;
    return (void*)p;
  };
  float* h = (float*)alloc((size_t)kRows * kD * 4);
  float* qkv = (float*)alloc((size_t)kRows * kQKV * 4);
  float* aop = (float*)alloc((size_t)2 * kRows * kD * 4);     // Wao partials
  float* res1 = (float*)alloc((size_t)kRows * kD * 4);
  float* cwop = (float*)alloc((size_t)4 * kRows * kD * 4);    // Wo partials
  float* zb = (float*)alloc((size_t)kND * kB * 384 * 4);
  float* da = (float*)alloc((size_t)kB * kND * 4);
  float* ub = (float*)alloc((size_t)kRows * 128 * 4);         // lora-up (full)
  float* iap = (float*)alloc((size_t)4 * kRows * 128 * 4);    // lora-dn parts
  float* vvb = (float*)alloc((size_t)kRows * 128 * 4);
  float* Mm = (float*)alloc((size_t)kNE * kE * 64 * 4);
  float* cc = (float*)alloc(64);
  short* n1h = (short*)alloc((size_t)kRows * kD * 2);
  short* n1l = (short*)alloc((size_t)kRows * kD * 2);
  short* n2h = (short*)alloc((size_t)kRows * kD * 2);
  short* n2l = (short*)alloc((size_t)kRows * kD * 2);
  short* inth = (short*)alloc((size_t)kRows * kH * 2);
  short* intl = (short*)alloc((size_t)kRows * kH * 2);
  short* pooledh = (short*)alloc((size_t)kND * kB * kD * 2);
  short* pooledl = (short*)alloc((size_t)kND * kB * kD * 2);
  // packed weights (frag-linear). wi/wo buffers carry lora tails (fused N).
  short* qkvph = (short*)alloc((size_t)144 * 24 * 512 * 2);
  short* qkvpl = (short*)alloc((size_t)144 * 24 * 512 * 2);
  short* waoph = (short*)alloc((size_t)48 * 24 * 512 * 2);
  short* waopl = (short*)alloc((size_t)48 * 24 * 512 * 2);
  short* wiph = (short*)alloc((size_t)200 * 24 * 512 * 2);   // 192 wi + 8 lu
  short* wipl = (short*)alloc((size_t)200 * 24 * 512 * 2);
  short* woph = (short*)alloc((size_t)56 * 96 * 512 * 2);    // 48 wo + 8 ld
  short* wopl = (short*)alloc((size_t)56 * 96 * 512 * 2);
  short* cw1ph = (short*)alloc((size_t)336 * 24 * 512 * 2);
  short* cw1pl = (short*)alloc((size_t)336 * 24 * 512 * 2);
  short* luph = wiph + (size_t)192 * 24 * 512;
  short* lupl = wipl + (size_t)192 * 24 * 512;
  short* ldph = woph + (size_t)48 * 96 * 512;
  short* ldpl = wopl + (size_t)48 * 96 * 512;

  concat_k<<<(kRows * kD + 255) / 256, 256, 0, stream>>>(region, cls, h);
  cc_k<<<1, 32, 0, stream>>>(mask, cc);
  mmat_k<<<kNE * kE, 256, 0, stream>>>(Adn, Bup, Mm);

  const int nDD = kD * kD;
  const int nDH = kD * kH;

  ln_bf_k<<<kRows, 256, 0, stream>>>(h, ln1g, ln1b, n1h, n1l, 1e-12f);

  for (int i = 0; i < kL; i++) {
    int le = i >> 1;
    bool even = (i % 2) == 0;
    pack_layer_k<<<3456, 256, 0, stream>>>(
        Wq + (long)i * nDD, Wk + (long)i * nDD, Wv + (long)i * nDD,
        Wao + (long)i * nDD, Wi + (long)i * nDH, Wo + (long)i * nDH, qkvph,
        qkvpl, waoph, waopl, wiph, wipl, woph, wopl);
    if (even) {
      pack_pad_k<<<48, 256, 0, stream>>>(Aup + (long)le * kE * 8 * kD, luph,
                                         lupl, 768);
      pack_pad_k<<<192, 256, 0, stream>>>(Adn + (long)le * kE * 8 * kH, ldph,
                                          ldpl, 3072);
      pack_w_k<<<(336 * 24) / 4, 256, 0, stream>>>(
          cW1 + (long)le * kND * 384 * kD, cw1ph, cw1pl, 768, 336 * 24);
    }

    // QKV (N=2304): 36x30 = 1080 blocks (64x64 tiles)
    gemm_hl<64, 64, 0><<<dim3(36, 30), 256, 0, stream>>>(
        n1h, n1l, qkvph, qkvpl, nullptr, qkv, nullptr, nullptr, nullptr, 768,
        kQKV, 0, 0, 0, kBIG, 0, 0, 0, 0, 0);
    attn_k<<<kB * kNH, 256, 0, stream>>>(qkv, bq + i * kD, bk + i * kD,
                                         bv + i * kD, n1h, n1l);
    // Wao split-K x2: 12x30x2 = 720 blocks
    gemm_hl<64, 64, 1><<<dim3(12, 30, 2), 256, 0, stream>>>(
        n1h, n1l, waoph, waopl, nullptr, aop, nullptr, nullptr, nullptr, 768,
        kD, 0, 0, 384, kBIG, 0, 0, 0, kPS, 0);
    addln_bf_k<<<kRows, 256, 0, stream>>>(aop, bao + i * kD, h, ln2g + i * kD,
                                          ln2b + i * kD, res1, n2h, n2l, 1e-12f);
    // Wi (+ fused LoRA-up on even layers): N=3200 or 3072 -> 50/48 x 30
    gemm_hl<64, 64, 0><<<dim3(even ? 50 : 48, 30), 256, 0, stream>>>(
        n2h, n2l, wiph, wipl, bi + i * kH, nullptr, inth, intl, ub, 768, kH,
        128, 1, 0, even ? 3072 : kBIG, 0, 0, 0, 0, 0);
    // Wo (+ fused LoRA-down on even layers), split-K x4: 14/12 x 30 x 4
    gemm_hl<64, 64, 1><<<dim3(even ? 14 : 12, 30, 4), 256, 0, stream>>>(
        inth, intl, woph, wopl, nullptr, cwop, nullptr, nullptr, iap, 3072, kD,
        128, 0, 768, even ? 768 : kBIG, 0, 0, 0, kPS, kPSL);
    if (even) {
      pool_k<<<kND * kB, 256, 0, stream>>>(aop, bao + i * kD, mask, cc, pooledh,
                                           pooledl);
      // batched classifier GEMM: per disease d, M=64, N=384, K=768
      gemm_hl<64, 64, 2><<<dim3(6, 1, 14), 256, 0, stream>>>(
          pooledh, pooledl, cw1ph, cw1pl, cb1 + (long)le * kND * 384, zb,
          nullptr, nullptr, nullptr, 768, 384, 0, 0, 0, kBIG, (long)64 * kD,
          (long)576 * 512, 384, (long)64 * 384, 0);
      cls2_k<<<kND * kB, 256, 0, stream>>>(zb, clng + (long)le * kND * 384,
                                           clnb + (long)le * kND * 384,
                                           cW2 + (long)le * kND * 384,
                                           cb2 + le * kND, da);
      vcomb_k<<<(kRows * 120 + 255) / 256, 256, 0, stream>>>(
          ub, iap, Mm + le * kE * 64, vvb);
      finaleven_k<<<kRows, 256, 0, stream>>>(
          cwop, bo + i * kD, res1, vvb, Bdn + (long)le * kE * kD * 8, da, mask,
          h, ln1g + (i + 1) * kD, ln1b + (i + 1) * kD, n1h, n1l);
    } else if (i < kL - 1) {
      ln_parts_k<<<kRows, 256, 0, stream>>>(cwop, bo + i * kD, res1, h,
                                            ln1g + (i + 1) * kD,
                                            ln1b + (i + 1) * kD, n1h, n1l,
                                            1e-12f);
    } else {
      ln_row_k<<<kRows, 256, 0, stream>>>(cwop, bo + i * kD, res1, fg, fb, out,
                                          1e-12f);
    }
  }
}

// Round 13
// 3013.365 us; speedup vs baseline: 1.0550x; 1.0180x over previous
//
#include <hip/hip_runtime.h>

namespace {

constexpr int kB = 64, kSR = 29, kS = 30, kD = 768, kH = 3072, kL = 12;
constexpr int kNH = 12, kND = 14, kE = 15, kNE = 6;
constexpr int kRows = kB * kS;  // 1920
constexpr int kQKV = 2304;
constexpr long kPS = (long)kRows * kD;    // partial stride (fp32 elems)
constexpr long kPSL = (long)kRows * 128;  // lora partial stride
constexpr int kBIG = 1 << 30;

typedef __attribute__((ext_vector_type(8))) short s16x8;
typedef __attribute__((ext_vector_type(4))) float fx4;

__device__ __forceinline__ float gelu_f(float x) {
  return 0.5f * x * (1.0f + erff(x * 0.70710678118654752f));
}

__device__ __forceinline__ unsigned short f2bf_u(float x) {
  union { float f; unsigned u; } v;
  v.f = x;
  unsigned r = v.u + 0x7fffu + ((v.u >> 16) & 1u);
  return (unsigned short)(r >> 16);
}
__device__ __forceinline__ float bfu2f(unsigned short h) {
  union { unsigned u; float f; } v;
  v.u = ((unsigned)h) << 16;
  return v.f;
}

__device__ __forceinline__ void g2l16(const short* g, short* l) {
  __builtin_amdgcn_global_load_lds(
      (const __attribute__((address_space(1))) unsigned int*)g,
      (__attribute__((address_space(3))) unsigned int*)l, 16, 0, 0);
}

// XCD-aware bijective block swizzle (8 XCDs).
__device__ __forceinline__ void swz_block(int& bx, int& by, int& bz) {
  int gx = gridDim.x, gy = gridDim.y;
  int nwg = gx * gy * (int)gridDim.z;
  int orig = blockIdx.x + gx * (blockIdx.y + gy * blockIdx.z);
  int q = nwg >> 3, r = nwg & 7;
  int xcd = orig & 7, idx = orig >> 3;
  int s = (xcd < r ? xcd * (q + 1) : r * (q + 1) + (xcd - r) * q) + idx;
  bx = s % gx;
  int t2 = s / gx;
  by = t2 % gy;
  bz = t2 / gy;
}

__device__ __forceinline__ float block_sum(float v) {
  __shared__ float sb[4];
#pragma unroll
  for (int o = 32; o > 0; o >>= 1) v += __shfl_down(v, o, 64);
  int w = threadIdx.x >> 6;
  __syncthreads();
  if ((threadIdx.x & 63) == 0) sb[w] = v;
  __syncthreads();
  return sb[0] + sb[1] + sb[2] + sb[3];
}

__device__ __forceinline__ float dot8(const float* __restrict__ p,
                                      const float* __restrict__ q) {
  float4 x = *(const float4*)p;
  float4 y = *(const float4*)(p + 4);
  return x.x * q[0] + x.y * q[1] + x.z * q[2] + x.w * q[3] +
         y.x * q[4] + y.y * q[5] + y.z * q[6] + y.w * q[7];
}

// ---------------------------------------------------------------------------
// MFMA GEMM, C = A @ B^T, hi/lo bf16 planes, 3-pass (hh+hl+lh ~ fp32).
// A: row-major [M][K] planes. B: PRE-PACKED fragment-linear planes.
// Tile 64x64: DOUBLE-buffered LDS (32KB -> ~5 blocks/CU) with issue-ahead:
// stage for step s+1 is issued before compute of step s, so the vmcnt drain
// at the end-of-step barrier overlaps this block's MFMA, and the remaining
// exposed latency overlaps other co-resident blocks' compute (m114).
// 4 waves (2x2). FUSED-N: columns >= nsplit route to C2 (fp32, ldc2).
// MODE: 0 plain, 1 split-K partial buffers, 2 batched over bz.
// ---------------------------------------------------------------------------
template <int BM, int BN, int MODE>
__global__ __launch_bounds__(256) void gemm_hl(
    const short* __restrict__ Ah, const short* __restrict__ Al,
    const short* __restrict__ Bh, const short* __restrict__ Bl,
    const float* __restrict__ bias, float* __restrict__ Cf,
    short* __restrict__ Ch, short* __restrict__ Cl, float* __restrict__ C2,
    int K, int ldc, int ldc2, int act, int kchunk, int nsplit, long bsA,
    long bsB, long bsBias, long bsC, long bsC2) {
  constexpr int MFR = BM / 16, NFR = BN / 16;
  constexpr int NA = 2 * MFR, NB = 2 * NFR, LPW = (NA + NB) / 4;
  constexpr int MF_W = MFR / 2, NF_W = NFR / 2;
  constexpr int ABUF = 2 * MFR * 512, BBUF = 2 * NFR * 512;
  __shared__ __align__(16) short As[2][2][MFR][512];
  __shared__ __align__(16) short Bs[2][2][NFR][512];
  int bx, by, bz;
  swz_block(bx, by, bz);
  const int t = threadIdx.x, w = t >> 6, lane = t & 63;
  const int lr = lane & 15, lg = lane >> 4;
  const int m0 = by * BM, n0 = bx * BN;
  const int kst = K >> 5;
  int k0 = 0;
  if (MODE == 1) {
    k0 = bz * kchunk;
    Cf += bz * bsC;
    C2 += bz * bsC2;
  }
  if (MODE == 2) {
    Ah += bz * bsA;
    Al += bz * bsA;
    Bh += bz * bsB;
    Bl += bz * bsB;
    if (bias) bias += bz * bsBias;
    Cf += bz * bsC;
  }
  const int nsteps = (MODE == 1 ? kchunk : K) >> 5;
  const int wmf = (w & 1) * MF_W, wnf = (w >> 1) * NF_W;

  const short* gp[LPW];
  short* lp[LPW];
  int bo[LPW], adv[LPW];
#pragma unroll
  for (int q = 0; q < LPW; q++) {
    int f = w * LPW + q;
    if (f < NA) {
      int p = f & 1, mf = f >> 1;
      gp[q] = (p ? Al : Ah) + (size_t)(m0 + mf * 16 + lr) * K + k0 + lg * 8;
      lp[q] = &As[0][p][mf][0];
      bo[q] = ABUF;
      adv[q] = 32;
    } else {
      int fb = f - NA, p = fb & 1, nf = fb >> 1;
      gp[q] = (p ? Bl : Bh) + ((size_t)(n0 / 16 + nf) * kst + (k0 >> 5)) * 512 +
              lane * 8;
      lp[q] = &Bs[0][p][nf][0];
      bo[q] = BBUF;
      adv[q] = 512;
    }
  }

  auto stage = [&](int bufidx) {
#pragma unroll
    for (int q = 0; q < LPW; q++) {
      g2l16(gp[q], lp[q] + bufidx * bo[q]);
      gp[q] += adv[q];
    }
  };

  fx4 acc[MF_W][NF_W];
#pragma unroll
  for (int i = 0; i < MF_W; i++)
#pragma unroll
    for (int j = 0; j < NF_W; j++) acc[i][j] = (fx4)0.f;

  // prologue: stage step 0 into buf0
  stage(0);
  __syncthreads();

  int cur = 0;
  for (int s = 0; s < nsteps; s++) {
    if (s + 1 < nsteps) stage(cur ^ 1);
    s16x8 af[MF_W][2], bf[NF_W][2];
#pragma unroll
    for (int fm = 0; fm < MF_W; fm++) {
      af[fm][0] = *(const s16x8*)&As[cur][0][wmf + fm][lane * 8];
      af[fm][1] = *(const s16x8*)&As[cur][1][wmf + fm][lane * 8];
    }
#pragma unroll
    for (int fn = 0; fn < NF_W; fn++) {
      bf[fn][0] = *(const s16x8*)&Bs[cur][0][wnf + fn][lane * 8];
      bf[fn][1] = *(const s16x8*)&Bs[cur][1][wnf + fn][lane * 8];
    }
#pragma unroll
    for (int fm = 0; fm < MF_W; fm++)
#pragma unroll
      for (int fn = 0; fn < NF_W; fn++)
        acc[fm][fn] = __builtin_amdgcn_mfma_f32_16x16x32_bf16(
            af[fm][0], bf[fn][0], acc[fm][fn], 0, 0, 0);
#pragma unroll
    for (int fm = 0; fm < MF_W; fm++)
#pragma unroll
      for (int fn = 0; fn < NF_W; fn++)
        acc[fm][fn] = __builtin_amdgcn_mfma_f32_16x16x32_bf16(
            af[fm][0], bf[fn][1], acc[fm][fn], 0, 0, 0);
#pragma unroll
    for (int fm = 0; fm < MF_W; fm++)
#pragma unroll
      for (int fn = 0; fn < NF_W; fn++)
        acc[fm][fn] = __builtin_amdgcn_mfma_f32_16x16x32_bf16(
            af[fm][1], bf[fn][0], acc[fm][fn], 0, 0, 0);
    __syncthreads();
    cur ^= 1;
  }

  const int orow = (lane >> 4) * 4;
  const bool rg2 = (n0 >= nsplit);
#pragma unroll
  for (int fm = 0; fm < MF_W; fm++) {
#pragma unroll
    for (int fn = 0; fn < NF_W; fn++) {
      int col = n0 + (wnf + fn) * 16 + lr;
      if (MODE == 1) {
        if (rg2) {
          int c2 = col - nsplit;
#pragma unroll
          for (int j = 0; j < 4; j++) {
            int row = m0 + (wmf + fm) * 16 + orow + j;
            C2[(size_t)row * ldc2 + c2] = acc[fm][fn][j];
          }
        } else {
#pragma unroll
          for (int j = 0; j < 4; j++) {
            int row = m0 + (wmf + fm) * 16 + orow + j;
            Cf[(size_t)row * ldc + col] = acc[fm][fn][j];
          }
        }
      } else if (rg2) {
        int c2 = col - nsplit;
#pragma unroll
        for (int j = 0; j < 4; j++) {
          int row = m0 + (wmf + fm) * 16 + orow + j;
          C2[(size_t)row * ldc2 + c2] = acc[fm][fn][j];
        }
      } else {
        float bv = bias ? bias[col] : 0.f;
#pragma unroll
        for (int j = 0; j < 4; j++) {
          int row = m0 + (wmf + fm) * 16 + orow + j;
          float v = acc[fm][fn][j] + bv;
          if (act) v = gelu_f(v);
          size_t idx = (size_t)row * ldc + col;
          if (Cf) Cf[idx] = v;
          if (Ch) {
            unsigned short hb = f2bf_u(v);
            Ch[idx] = (short)hb;
            Cl[idx] = (short)f2bf_u(v - bfu2f(hb));
          }
        }
      }
    }
  }
}

// ---------- weight packing ----------
__device__ __forceinline__ void pack_store(const float* src, short* ph,
                                           short* pl, size_t o) {
  float4 a = *(const float4*)src;
  float4 b = *(const float4*)(src + 4);
  float v[8] = {a.x, a.y, a.z, a.w, b.x, b.y, b.z, b.w};
  s16x8 hv, lv;
#pragma unroll
  for (int e = 0; e < 8; e++) {
    unsigned short h = f2bf_u(v[e]);
    hv[e] = (short)h;
    lv[e] = (short)f2bf_u(v[e] - bfu2f(h));
  }
  *(s16x8*)(ph + o) = hv;
  *(s16x8*)(pl + o) = lv;
}

// One dispatch packs all 4 per-layer weight matrices (13824 tiles).
__global__ __launch_bounds__(256) void pack_layer_k(
    const float* __restrict__ Wq, const float* __restrict__ Wk,
    const float* __restrict__ Wv, const float* __restrict__ Wao,
    const float* __restrict__ Wi, const float* __restrict__ Wo,
    short* __restrict__ qph, short* __restrict__ qpl, short* __restrict__ aph,
    short* __restrict__ apl, short* __restrict__ iph, short* __restrict__ ipl,
    short* __restrict__ oph, short* __restrict__ opl) {
  int tile = blockIdx.x * 4 + (threadIdx.x >> 6);
  int lane = threadIdx.x & 63;
  int lr = lane & 15, lg = lane >> 4;
  const float* src;
  short *ph, *pl;
  size_t o;
  if (tile < 3456) {
    int nf = tile / 24, ks = tile % 24;
    int row = nf * 16 + lr;
    const float* W = row < 768 ? Wq : row < 1536 ? Wk : Wv;
    int r = row < 768 ? row : row < 1536 ? row - 768 : row - 1536;
    src = W + (size_t)r * 768 + ks * 32 + lg * 8;
    ph = qph; pl = qpl;
    o = (size_t)tile * 512 + lane * 8;
  } else if (tile < 4608) {
    int idx = tile - 3456;
    int nf = idx / 24, ks = idx % 24;
    src = Wao + (size_t)(nf * 16 + lr) * 768 + ks * 32 + lg * 8;
    ph = aph; pl = apl;
    o = (size_t)idx * 512 + lane * 8;
  } else if (tile < 9216) {
    int idx = tile - 4608;
    int nf = idx / 24, ks = idx % 24;
    src = Wi + (size_t)(nf * 16 + lr) * 768 + ks * 32 + lg * 8;
    ph = iph; pl = ipl;
    o = (size_t)idx * 512 + lane * 8;
  } else {
    int idx = tile - 9216;
    int nf = idx / 96, ks = idx % 96;
    src = Wo + (size_t)(nf * 16 + lr) * 3072 + ks * 32 + lg * 8;
    ph = oph; pl = opl;
    o = (size_t)idx * 512 + lane * 8;
  }
  pack_store(src, ph, pl, o);
}

__global__ __launch_bounds__(256) void pack_w_k(const float* __restrict__ W,
                                                short* __restrict__ ph,
                                                short* __restrict__ pl, int K,
                                                int ntiles) {
  int tile = blockIdx.x * 4 + (threadIdx.x >> 6);
  if (tile >= ntiles) return;
  int kst = K >> 5;
  int nf = tile / kst, ks = tile - nf * kst;
  int lane = threadIdx.x & 63;
  int lr = lane & 15, lg = lane >> 4;
  const float* src = W + (size_t)(nf * 16 + lr) * K + ks * 32 + lg * 8;
  pack_store(src, ph, pl, (size_t)tile * 512 + lane * 8);
}

__global__ __launch_bounds__(256) void pack_pad_k(const float* __restrict__ W,
                                                  short* __restrict__ ph,
                                                  short* __restrict__ pl,
                                                  int K) {
  int tile = blockIdx.x * 4 + (threadIdx.x >> 6);
  int kst = K >> 5;
  if (tile >= 8 * kst) return;
  int nf = tile / kst, ks = tile - nf * kst;
  int lane = threadIdx.x & 63;
  int lr = lane & 15, lg = lane >> 4;
  int row = nf * 16 + lr;
  size_t o = (size_t)tile * 512 + lane * 8;
  if (row < 120) {
    pack_store(W + (size_t)row * K + ks * 32 + lg * 8, ph, pl, o);
  } else {
    *(s16x8*)(ph + o) = (s16x8)0;
    *(s16x8*)(pl + o) = (s16x8)0;
  }
}

__global__ __launch_bounds__(256) void concat_k(const float* __restrict__ rf,
                                                const float* __restrict__ cls,
                                                float* __restrict__ h) {
  int idx = blockIdx.x * 256 + threadIdx.x;
  if (idx >= kRows * kD) return;
  int d = idx % kD;
  int row = idx / kD;
  int s = row % kS;
  int b = row / kS;
  h[idx] = (s == 0) ? cls[d] : rf[((long)b * kSR + (s - 1)) * kD + d];
}

__global__ void cc_k(const float* __restrict__ mask, float* __restrict__ cc) {
  int d = threadIdx.x;
  if (d < kND) {
    float s = 0.f;
    for (int r = 0; r < kSR; r++) s += mask[r * kND + d];
    cc[d] = s;
  }
}

__global__ __launch_bounds__(256) void mmat_k(const float* __restrict__ Adn,
                                              const float* __restrict__ Bup,
                                              float* __restrict__ Mm) {
  int g = blockIdx.x;
  int t = threadIdx.x;
  int pair = t & 63;
  int quarter = t >> 6;
  int rp = pair >> 3, r = pair & 7;
  const float* ad = Adn + (long)(g * 8 + rp) * kH;
  const float* bu = Bup + (long)g * kH * 8 + r;
  float acc = 0.f;
  for (int hh = quarter * 768; hh < quarter * 768 + 768; hh++)
    acc += ad[hh] * bu[hh * 8];
  __shared__ float red[256];
  red[t] = acc;
  __syncthreads();
  if (t < 64) Mm[g * 64 + pair] = red[t] + red[t + 64] + red[t + 128] + red[t + 192];
}

// plain LN(x) -> hi/lo planes (layer 0 only)
__global__ __launch_bounds__(256) void ln_bf_k(const float* __restrict__ x,
                                               const float* __restrict__ g,
                                               const float* __restrict__ b,
                                               short* __restrict__ yh,
                                               short* __restrict__ yl,
                                               float eps) {
  int row = blockIdx.x;
  int t = threadIdx.x;
  long rb = (long)row * kD;
  float v0 = x[rb + t], v1 = x[rb + t + 256], v2 = x[rb + t + 512];
  float m = block_sum(v0 + v1 + v2) * (1.0f / 768.0f);
  float d0 = v0 - m, d1 = v1 - m, d2 = v2 - m;
  float q = block_sum(d0 * d0 + d1 * d1 + d2 * d2);
  float inv = rsqrtf(q * (1.0f / 768.0f) + eps);
#pragma unroll
  for (int c = 0; c < 3; c++) {
    int tt = t + c * 256;
    float dd = (c == 0 ? d0 : c == 1 ? d1 : d2);
    float val = dd * inv * g[tt] + b[tt];
    unsigned short hb = f2bf_u(val);
    yh[rb + tt] = (short)hb;
    yl[rb + tt] = (short)f2bf_u(val - bfu2f(hb));
  }
}

// odd layers: h = sum4(cwop) + bo + res1 ; n1 = LN(h) -> planes
__global__ __launch_bounds__(256) void ln_parts_k(
    const float* __restrict__ parts, const float* __restrict__ b2,
    const float* __restrict__ r2, float* __restrict__ hout,
    const float* __restrict__ g, const float* __restrict__ b,
    short* __restrict__ yh, short* __restrict__ yl, float eps) {
  int row = blockIdx.x;
  int t = threadIdx.x;
  long rb = (long)row * kD;
  float v0, v1, v2;
  {
    float s0 = 0, s1 = 0, s2 = 0;
#pragma unroll
    for (int p = 0; p < 4; p++) {
      s0 += parts[p * kPS + rb + t];
      s1 += parts[p * kPS + rb + t + 256];
      s2 += parts[p * kPS + rb + t + 512];
    }
    v0 = s0 + b2[t] + r2[rb + t];
    v1 = s1 + b2[t + 256] + r2[rb + t + 256];
    v2 = s2 + b2[t + 512] + r2[rb + t + 512];
  }
  hout[rb + t] = v0;
  hout[rb + t + 256] = v1;
  hout[rb + t + 512] = v2;
  float m = block_sum(v0 + v1 + v2) * (1.0f / 768.0f);
  float d0 = v0 - m, d1 = v1 - m, d2 = v2 - m;
  float q = block_sum(d0 * d0 + d1 * d1 + d2 * d2);
  float inv = rsqrtf(q * (1.0f / 768.0f) + eps);
#pragma unroll
  for (int c = 0; c < 3; c++) {
    int tt = t + c * 256;
    float dd = (c == 0 ? d0 : c == 1 ? d1 : d2);
    float val = dd * inv * g[tt] + b[tt];
    unsigned short hb = f2bf_u(val);
    yh[rb + tt] = (short)hb;
    yl[rb + tt] = (short)f2bf_u(val - bfu2f(hb));
  }
}

// final: out = LN(sum4(cwop) + bo + res1)
__global__ __launch_bounds__(256) void ln_row_k(
    const float* __restrict__ parts, const float* __restrict__ b2,
    const float* __restrict__ r2, const float* __restrict__ g,
    const float* __restrict__ b, float* __restrict__ y, float eps) {
  int row = blockIdx.x;
  int t = threadIdx.x;
  long rb = (long)row * kD;
  float s0 = 0, s1 = 0, s2 = 0;
#pragma unroll
  for (int p = 0; p < 4; p++) {
    s0 += parts[p * kPS + rb + t];
    s1 += parts[p * kPS + rb + t + 256];
    s2 += parts[p * kPS + rb + t + 512];
  }
  float v0 = s0 + b2[t] + r2[rb + t];
  float v1 = s1 + b2[t + 256] + r2[rb + t + 256];
  float v2 = s2 + b2[t + 512] + r2[rb + t + 512];
  float m = block_sum(v0 + v1 + v2) * (1.0f / 768.0f);
  float d0 = v0 - m, d1 = v1 - m, d2 = v2 - m;
  float q = block_sum(d0 * d0 + d1 * d1 + d2 * d2);
  float inv = rsqrtf(q * (1.0f / 768.0f) + eps);
  y[rb + t] = d0 * inv * g[t] + b[t];
  y[rb + t + 256] = d1 * inv * g[t + 256] + b[t + 256];
  y[rb + t + 512] = d2 * inv * g[t + 512] + b[t + 512];
}

// res1 = sum2(aop) + abias + h ; n2 = LN(res1) -> planes
__global__ __launch_bounds__(256) void addln_bf_k(
    const float* __restrict__ aparts, const float* __restrict__ abias,
    const float* __restrict__ hh, const float* __restrict__ g,
    const float* __restrict__ b, float* __restrict__ r1,
    short* __restrict__ n2h, short* __restrict__ n2l, float eps) {
  int row = blockIdx.x;
  int t = threadIdx.x;
  long rb = (long)row * kD;
  float v0 = aparts[rb + t] + aparts[kPS + rb + t] + abias[t] + hh[rb + t];
  float v1 = aparts[rb + t + 256] + aparts[kPS + rb + t + 256] + abias[t + 256] +
             hh[rb + t + 256];
  float v2 = aparts[rb + t + 512] + aparts[kPS + rb + t + 512] + abias[t + 512] +
             hh[rb + t + 512];
  r1[rb + t] = v0;
  r1[rb + t + 256] = v1;
  r1[rb + t + 512] = v2;
  float m = block_sum(v0 + v1 + v2) * (1.0f / 768.0f);
  float d0 = v0 - m, d1 = v1 - m, d2 = v2 - m;
  float q = block_sum(d0 * d0 + d1 * d1 + d2 * d2);
  float inv = rsqrtf(q * (1.0f / 768.0f) + eps);
#pragma unroll
  for (int c = 0; c < 3; c++) {
    int tt = t + c * 256;
    float dd = (c == 0 ? d0 : c == 1 ? d1 : d2);
    float val = dd * inv * g[tt] + b[tt];
    unsigned short hb = f2bf_u(val);
    n2h[rb + tt] = (short)hb;
    n2l[rb + tt] = (short)f2bf_u(val - bfu2f(hb));
  }
}

// One block per (b, head). Reads qkv [1920][2304], adds biases inline.
__global__ __launch_bounds__(256) void attn_k(const float* __restrict__ qkv,
                                              const float* __restrict__ bq,
                                              const float* __restrict__ bk,
                                              const float* __restrict__ bv,
                                              short* __restrict__ oh,
                                              short* __restrict__ ol) {
  int blk = blockIdx.x;
  int b = blk / kNH, hh = blk % kNH;
  __shared__ float qs[30][65], ks[30][65], vs[30][65], ps[30][32];
  int t = threadIdx.x;
  long ibase = (long)b * kS * kQKV + hh * 64;
  long obase = (long)b * kS * kD + hh * 64;
  for (int idx = t; idx < 1920; idx += 256) {
    int s = idx >> 6, d = idx & 63;
    long a = ibase + (long)s * kQKV + d;
    int bcol = hh * 64 + d;
    qs[s][d] = qkv[a] + bq[bcol];
    ks[s][d] = qkv[a + 768] + bk[bcol];
    vs[s][d] = qkv[a + 1536] + bv[bcol];
  }
  __syncthreads();
  for (int idx = t; idx < 900; idx += 256) {
    int r = idx / 30, c = idx % 30;
    float acc = 0.f;
#pragma unroll
    for (int d = 0; d < 64; d++) acc += qs[r][d] * ks[c][d];
    ps[r][c] = acc * 0.125f;
  }
  __syncthreads();
  if (t < 30) {
    float mx = -1e30f;
#pragma unroll
    for (int c = 0; c < 30; c++) mx = fmaxf(mx, ps[t][c]);
    float sm = 0.f;
#pragma unroll
    for (int c = 0; c < 30; c++) sm += expf(ps[t][c] - mx);
    float inv = 1.0f / sm;
#pragma unroll
    for (int c = 0; c < 30; c++) ps[t][c] = expf(ps[t][c] - mx) * inv;
  }
  __syncthreads();
  for (int idx = t; idx < 1920; idx += 256) {
    int r = idx >> 6, d = idx & 63;
    float acc = 0.f;
#pragma unroll
    for (int c = 0; c < 30; c++) acc += ps[r][c] * vs[c][d];
    long a = obase + (long)r * kD + d;
    unsigned short hb = f2bf_u(acc);
    oh[a] = (short)hb;
    ol[a] = (short)f2bf_u(acc - bfu2f(hb));
  }
}

// pooled (row d*64+b) = (sum_r mask*sum2(aop))/cc + bao -> hi/lo planes
__global__ __launch_bounds__(256) void pool_k(const float* __restrict__ aparts,
                                              const float* __restrict__ bao,
                                              const float* __restrict__ mask,
                                              const float* __restrict__ cc,
                                              short* __restrict__ ph,
                                              short* __restrict__ pl) {
  int blk = blockIdx.x;
  int d = blk >> 6, b = blk & 63;
  __shared__ float mr[32];
  int t = threadIdx.x;
  if (t < kSR) mr[t] = mask[t * kND + d];
  __syncthreads();
  float inv = 1.0f / cc[d];
  for (int hd = t; hd < kD; hd += 256) {
    float acc = 0.f;
    for (int r = 0; r < kSR; r++) {
      long o = ((long)b * kS + 1 + r) * kD + hd;
      acc += mr[r] * (aparts[o] + aparts[kPS + o]);
    }
    float v = acc * inv + bao[hd];
    unsigned short hb = f2bf_u(v);
    size_t o = (size_t)blk * kD + hd;
    ph[o] = (short)hb;
    pl[o] = (short)f2bf_u(v - bfu2f(hb));
  }
}

__global__ __launch_bounds__(256) void cls2_k(const float* __restrict__ z,
                                              const float* __restrict__ lng,
                                              const float* __restrict__ lnb,
                                              const float* __restrict__ w2,
                                              const float* __restrict__ b2,
                                              float* __restrict__ da) {
  int blk = blockIdx.x;
  int d = blk >> 6, b = blk & 63;
  int t = threadIdx.x;
  const float* zr = z + (long)blk * 384;
  float v0 = zr[t];
  float v1 = (t < 128) ? zr[256 + t] : 0.f;
  float m = block_sum(v0 + v1) * (1.0f / 384.0f);
  float d0 = v0 - m;
  float d1 = (t < 128) ? v1 - m : 0.f;
  float q = block_sum(d0 * d0 + d1 * d1);
  float inv = rsqrtf(q * (1.0f / 384.0f) + 1e-5f);
  const float* lg = lng + (long)d * 384;
  const float* lb = lnb + (long)d * 384;
  const float* wd = w2 + (long)d * 384;
  float p = gelu_f(d0 * inv * lg[t] + lb[t]) * wd[t];
  if (t < 128) p += gelu_f(d1 * inv * lg[256 + t] + lb[256 + t]) * wd[256 + t];
  float ps = block_sum(p);
  if (t == 0) da[b * kND + d] = (ps + b2[d] > 0.f) ? 1.f : 0.f;
}

// vv = sum4(iap) + SCALE * M_e @ u  (u single buffer from fused Wi)
__global__ __launch_bounds__(256) void vcomb_k(const float* __restrict__ ub,
                                               const float* __restrict__ iap,
                                               const float* __restrict__ Mm,
                                               float* __restrict__ vv) {
  int idx = blockIdx.x * 256 + threadIdx.x;
  if (idx >= kRows * 120) return;
  int row = idx / 120, c = idx % 120;
  int e = c >> 3, rp = c & 7;
  const float* Me = Mm + e * 64 + rp * 8;
  long rb = (long)row * 128;
  float acc = 0.f;
#pragma unroll
  for (int p = 0; p < 4; p++) acc += iap[p * kPSL + rb + c];
  const float* ur = ub + rb + e * 8;
#pragma unroll
  for (int r = 0; r < 8; r++) acc += 2.0f * Me[r] * ur[r];
  vv[rb + c] = acc;
}

// even layers: base = sum4(cwop)+bo; expert loop; h = acc+res1; then
// n1 = LN(h, ln1g/ln1b of NEXT layer) -> planes (fused).
__global__ __launch_bounds__(256) void finaleven_k(
    const float* __restrict__ parts, const float* __restrict__ bo,
    const float* __restrict__ res1, const float* __restrict__ vv,
    const float* __restrict__ Bd, const float* __restrict__ da,
    const float* __restrict__ mask, float* __restrict__ h,
    const float* __restrict__ g1, const float* __restrict__ b1,
    short* __restrict__ n1h, short* __restrict__ n1l) {
  int row = blockIdx.x;
  int b = row / kS, s = row % kS;
  int t = threadIdx.x;
  __shared__ float w[16];
  __shared__ float vvs[120];
  if (t < 120) vvs[t] = vv[(long)row * 128 + t];
  if (t < kND) w[t] = (s >= 1) ? da[b * kND + t] * mask[(s - 1) * kND + t] : 0.f;
  if (t == kND) w[kND] = 1.f;
  __syncthreads();
  float wsum = 0.f;
#pragma unroll
  for (int e = 0; e < kE; e++) wsum += w[e];
  float winv = 1.0f / wsum;
  long rb = (long)row * kD;
  float b0 = bo[t], b1v = bo[t + 256], b2v = bo[t + 512];
#pragma unroll
  for (int p = 0; p < 4; p++) {
    b0 += parts[p * kPS + rb + t];
    b1v += parts[p * kPS + rb + t + 256];
    b2v += parts[p * kPS + rb + t + 512];
  }
  float a0 = 0.f, a1 = 0.f, a2 = 0.f;
  for (int e = 0; e < kE; e++) {
    float we = w[e];
    if (we == 0.f) continue;
    const float* vr = vvs + e * 8;
    float y0 = b0 + 2.0f * dot8(Bd + ((long)(e * kD + t)) * 8, vr);
    float y1 = b1v + 2.0f * dot8(Bd + ((long)(e * kD + t + 256)) * 8, vr);
    float y2 = b2v + 2.0f * dot8(Bd + ((long)(e * kD + t + 512)) * 8, vr);
    float m = block_sum(y0 + y1 + y2) * (1.0f / 768.0f);
    float d0 = y0 - m, d1 = y1 - m, d2 = y2 - m;
    float q = block_sum(d0 * d0 + d1 * d1 + d2 * d2);
    float inv = rsqrtf(q * (1.0f / 768.0f) + 1e-5f);
    float sc = we * winv * inv;
    a0 += sc * d0;
    a1 += sc * d1;
    a2 += sc * d2;
  }
  float v0 = a0 + res1[rb + t];
  float v1 = a1 + res1[rb + t + 256];
  float v2 = a2 + res1[rb + t + 512];
  h[rb + t] = v0;
  h[rb + t + 256] = v1;
  h[rb + t + 512] = v2;
  float m = block_sum(v0 + v1 + v2) * (1.0f / 768.0f);
  float d0 = v0 - m, d1 = v1 - m, d2 = v2 - m;
  float q = block_sum(d0 * d0 + d1 * d1 + d2 * d2);
  float inv = rsqrtf(q * (1.0f / 768.0f) + 1e-12f);
#pragma unroll
  for (int c = 0; c < 3; c++) {
    int tt = t + c * 256;
    float dd = (c == 0 ? d0 : c == 1 ? d1 : d2);
    float val = dd * inv * g1[tt] + b1[tt];
    unsigned short hb = f2bf_u(val);
    n1h[rb + tt] = (short)hb;
    n1l[rb + tt] = (short)f2bf_u(val - bfu2f(hb));
  }
}

}  // namespace

extern "C" void kernel_launch(void* const* d_in, const int* in_sizes, int n_in,
                              void* d_out, int out_size, void* d_ws, size_t ws_size,
                              hipStream_t stream) {
  const float* region = (const float*)d_in[0];
  const float* mask = (const float*)d_in[1];
  const float* cls = (const float*)d_in[2];
  const float* ln1g = (const float*)d_in[3];
  const float* ln1b = (const float*)d_in[4];
  const float* ln2g = (const float*)d_in[5];
  const float* ln2b = (const float*)d_in[6];
  const float* Wq = (const float*)d_in[7];
  const float* bq = (const float*)d_in[8];
  const float* Wk = (const float*)d_in[9];
  const float* bk = (const float*)d_in[10];
  const float* Wv = (const float*)d_in[11];
  const float* bv = (const float*)d_in[12];
  const float* Wao = (const float*)d_in[13];
  const float* bao = (const float*)d_in[14];
  const float* Wi = (const float*)d_in[15];
  const float* bi = (const float*)d_in[16];
  const float* Wo = (const float*)d_in[17];
  const float* bo = (const float*)d_in[18];
  const float* fg = (const float*)d_in[19];
  const float* fb = (const float*)d_in[20];
  const float* cW1 = (const float*)d_in[21];
  const float* cb1 = (const float*)d_in[22];
  const float* clng = (const float*)d_in[23];
  const float* clnb = (const float*)d_in[24];
  const float* cW2 = (const float*)d_in[25];
  const float* cb2 = (const float*)d_in[26];
  const float* Aup = (const float*)d_in[27];
  const float* Bup = (const float*)d_in[28];
  const float* Adn = (const float*)d_in[29];
  const float* Bdn = (const float*)d_in[30];
  float* out = (float*)d_out;

  char* wsb = (char*)d_ws;
  size_t off = 0;
  auto alloc = [&](size_t bytes) {
    char* p = wsb + off;
    off = (off + bytes + 255) & ~(size_t)255;
    return (void*)p;
  };
  float* h = (float*)alloc((size_t)kRows * kD * 4);
  float* qkv = (float*)alloc((size_t)kRows * kQKV * 4);
  float* aop = (float*)alloc((size_t)2 * kRows * kD * 4);     // Wao partials
  float* res1 = (float*)alloc((size_t)kRows * kD * 4);
  float* cwop = (float*)alloc((size_t)4 * kRows * kD * 4);    // Wo partials
  float* zb = (float*)alloc((size_t)kND * kB * 384 * 4);
  float* da = (float*)alloc((size_t)kB * kND * 4);
  float* ub = (float*)alloc((size_t)kRows * 128 * 4);         // lora-up (full)
  float* iap = (float*)alloc((size_t)4 * kRows * 128 * 4);    // lora-dn parts
  float* vvb = (float*)alloc((size_t)kRows * 128 * 4);
  float* Mm = (float*)alloc((size_t)kNE * kE * 64 * 4);
  float* cc = (float*)alloc(64);
  short* n1h = (short*)alloc((size_t)kRows * kD * 2);
  short* n1l = (short*)alloc((size_t)kRows * kD * 2);
  short* n2h = (short*)alloc((size_t)kRows * kD * 2);
  short* n2l = (short*)alloc((size_t)kRows * kD * 2);
  short* inth = (short*)alloc((size_t)kRows * kH * 2);
  short* intl = (short*)alloc((size_t)kRows * kH * 2);
  short* pooledh = (short*)alloc((size_t)kND * kB * kD * 2);
  short* pooledl = (short*)alloc((size_t)kND * kB * kD * 2);
  // packed weights (frag-linear). wi/wo buffers carry lora tails (fused N).
  short* qkvph = (short*)alloc((size_t)144 * 24 * 512 * 2);
  short* qkvpl = (short*)alloc((size_t)144 * 24 * 512 * 2);
  short* waoph = (short*)alloc((size_t)48 * 24 * 512 * 2);
  short* waopl = (short*)alloc((size_t)48 * 24 * 512 * 2);
  short* wiph = (short*)alloc((size_t)200 * 24 * 512 * 2);   // 192 wi + 8 lu
  short* wipl = (short*)alloc((size_t)200 * 24 * 512 * 2);
  short* woph = (short*)alloc((size_t)56 * 96 * 512 * 2);    // 48 wo + 8 ld
  short* wopl = (short*)alloc((size_t)56 * 96 * 512 * 2);
  short* cw1ph = (short*)alloc((size_t)336 * 24 * 512 * 2);
  short* cw1pl = (short*)alloc((size_t)336 * 24 * 512 * 2);
  short* luph = wiph + (size_t)192 * 24 * 512;
  short* lupl = wipl + (size_t)192 * 24 * 512;
  short* ldph = woph + (size_t)48 * 96 * 512;
  short* ldpl = wopl + (size_t)48 * 96 * 512;

  concat_k<<<(kRows * kD + 255) / 256, 256, 0, stream>>>(region, cls, h);
  cc_k<<<1, 32, 0, stream>>>(mask, cc);
  mmat_k<<<kNE * kE, 256, 0, stream>>>(Adn, Bup, Mm);

  const int nDD = kD * kD;
  const int nDH = kD * kH;

  ln_bf_k<<<kRows, 256, 0, stream>>>(h, ln1g, ln1b, n1h, n1l, 1e-12f);

  for (int i = 0; i < kL; i++) {
    int le = i >> 1;
    bool even = (i % 2) == 0;
    pack_layer_k<<<3456, 256, 0, stream>>>(
        Wq + (long)i * nDD, Wk + (long)i * nDD, Wv + (long)i * nDD,
        Wao + (long)i * nDD, Wi + (long)i * nDH, Wo + (long)i * nDH, qkvph,
        qkvpl, waoph, waopl, wiph, wipl, woph, wopl);
    if (even) {
      pack_pad_k<<<48, 256, 0, stream>>>(Aup + (long)le * kE * 8 * kD, luph,
                                         lupl, 768);
      pack_pad_k<<<192, 256, 0, stream>>>(Adn + (long)le * kE * 8 * kH, ldph,
                                          ldpl, 3072);
      pack_w_k<<<(336 * 24) / 4, 256, 0, stream>>>(
          cW1 + (long)le * kND * 384 * kD, cw1ph, cw1pl, 768, 336 * 24);
    }

    // QKV (N=2304): 36x30 = 1080 blocks (64x64 tiles)
    gemm_hl<64, 64, 0><<<dim3(36, 30), 256, 0, stream>>>(
        n1h, n1l, qkvph, qkvpl, nullptr, qkv, nullptr, nullptr, nullptr, 768,
        kQKV, 0, 0, 0, kBIG, 0, 0, 0, 0, 0);
    attn_k<<<kB * kNH, 256, 0, stream>>>(qkv, bq + i * kD, bk + i * kD,
                                         bv + i * kD, n1h, n1l);
    // Wao split-K x2: 12x30x2 = 720 blocks
    gemm_hl<64, 64, 1><<<dim3(12, 30, 2), 256, 0, stream>>>(
        n1h, n1l, waoph, waopl, nullptr, aop, nullptr, nullptr, nullptr, 768,
        kD, 0, 0, 384, kBIG, 0, 0, 0, kPS, 0);
    addln_bf_k<<<kRows, 256, 0, stream>>>(aop, bao + i * kD, h, ln2g + i * kD,
                                          ln2b + i * kD, res1, n2h, n2l, 1e-12f);
    // Wi (+ fused LoRA-up on even layers): N=3200 or 3072 -> 50/48 x 30
    gemm_hl<64, 64, 0><<<dim3(even ? 50 : 48, 30), 256, 0, stream>>>(
        n2h, n2l, wiph, wipl, bi + i * kH, nullptr, inth, intl, ub, 768, kH,
        128, 1, 0, even ? 3072 : kBIG, 0, 0, 0, 0, 0);
    // Wo (+ fused LoRA-down on even layers), split-K x4: 14/12 x 30 x 4
    gemm_hl<64, 64, 1><<<dim3(even ? 14 : 12, 30, 4), 256, 0, stream>>>(
        inth, intl, woph, wopl, nullptr, cwop, nullptr, nullptr, iap, 3072, kD,
        128, 0, 768, even ? 768 : kBIG, 0, 0, 0, kPS, kPSL);
    if (even) {
      pool_k<<<kND * kB, 256, 0, stream>>>(aop, bao + i * kD, mask, cc, pooledh,
                                           pooledl);
      // batched classifier GEMM: per disease d, M=64, N=384, K=768
      gemm_hl<64, 64, 2><<<dim3(6, 1, 14), 256, 0, stream>>>(
          pooledh, pooledl, cw1ph, cw1pl, cb1 + (long)le * kND * 384, zb,
          nullptr, nullptr, nullptr, 768, 384, 0, 0, 0, kBIG, (long)64 * kD,
          (long)576 * 512, 384, (long)64 * 384, 0);
      cls2_k<<<kND * kB, 256, 0, stream>>>(zb, clng + (long)le * kND * 384,
                                           clnb + (long)le * kND * 384,
                                           cW2 + (long)le * kND * 384,
                                           cb2 + le * kND, da);
      vcomb_k<<<(kRows * 120 + 255) / 256, 256, 0, stream>>>(
          ub, iap, Mm + le * kE * 64, vvb);
      finaleven_k<<<kRows, 256, 0, stream>>>(
          cwop, bo + i * kD, res1, vvb, Bdn + (long)le * kE * kD * 8, da, mask,
          h, ln1g + (i + 1) * kD, ln1b + (i + 1) * kD, n1h, n1l);
    } else if (i < kL - 1) {
      ln_parts_k<<<kRows, 256, 0, stream>>>(cwop, bo + i * kD, res1, h,
                                            ln1g + (i + 1) * kD,
                                            ln1b + (i + 1) * kD, n1h, n1l,
                                            1e-12f);
    } else {
      ln_row_k<<<kRows, 256, 0, stream>>>(cwop, bo + i * kD, res1, fg, fb, out,
                                          1e-12f);
    }
  }
}

// Round 14
// 2961.804 us; speedup vs baseline: 1.0734x; 1.0174x over previous
//
#include <hip/hip_runtime.h>

namespace {

constexpr int kB = 64, kSR = 29, kS = 30, kD = 768, kH = 3072, kL = 12;
constexpr int kNH = 12, kND = 14, kE = 15, kNE = 6;
constexpr int kRows = kB * kS;  // 1920
constexpr int kQKV = 2304;
constexpr long kPS = (long)kRows * kD;    // partial stride (fp32 elems)
constexpr long kPSL = (long)kRows * 128;  // lora partial stride
constexpr int kBIG = 1 << 30;

typedef __attribute__((ext_vector_type(8))) short s16x8;
typedef __attribute__((ext_vector_type(4))) float fx4;

__device__ __forceinline__ float gelu_f(float x) {
  return 0.5f * x * (1.0f + erff(x * 0.70710678118654752f));
}

__device__ __forceinline__ unsigned short f2bf_u(float x) {
  union { float f; unsigned u; } v;
  v.f = x;
  unsigned r = v.u + 0x7fffu + ((v.u >> 16) & 1u);
  return (unsigned short)(r >> 16);
}
__device__ __forceinline__ float bfu2f(unsigned short h) {
  union { unsigned u; float f; } v;
  v.u = ((unsigned)h) << 16;
  return v.f;
}

__device__ __forceinline__ void g2l16(const short* g, short* l) {
  __builtin_amdgcn_global_load_lds(
      (const __attribute__((address_space(1))) unsigned int*)g,
      (__attribute__((address_space(3))) unsigned int*)l, 16, 0, 0);
}

// XCD-aware bijective block swizzle (8 XCDs).
__device__ __forceinline__ void swz_block(int& bx, int& by, int& bz) {
  int gx = gridDim.x, gy = gridDim.y;
  int nwg = gx * gy * (int)gridDim.z;
  int orig = blockIdx.x + gx * (blockIdx.y + gy * blockIdx.z);
  int q = nwg >> 3, r = nwg & 7;
  int xcd = orig & 7, idx = orig >> 3;
  int s = (xcd < r ? xcd * (q + 1) : r * (q + 1) + (xcd - r) * q) + idx;
  bx = s % gx;
  int t2 = s / gx;
  by = t2 % gy;
  bz = t2 / gy;
}

__device__ __forceinline__ float block_sum(float v) {
  __shared__ float sb[4];
#pragma unroll
  for (int o = 32; o > 0; o >>= 1) v += __shfl_down(v, o, 64);
  int w = threadIdx.x >> 6;
  __syncthreads();
  if ((threadIdx.x & 63) == 0) sb[w] = v;
  __syncthreads();
  return sb[0] + sb[1] + sb[2] + sb[3];
}

__device__ __forceinline__ float dot8(const float* __restrict__ p,
                                      const float* __restrict__ q) {
  float4 x = *(const float4*)p;
  float4 y = *(const float4*)(p + 4);
  return x.x * q[0] + x.y * q[1] + x.z * q[2] + x.w * q[3] +
         y.x * q[4] + y.y * q[5] + y.z * q[6] + y.w * q[7];
}

// ---------------------------------------------------------------------------
// MFMA GEMM, C = A @ B^T, hi/lo bf16 planes, 3-pass (hh+hl+lh ~ fp32).
// A: row-major [M][K] planes. B: PRE-PACKED fragment-linear planes.
// Tile 64x64: DOUBLE-buffered LDS (32KB -> ~5 blocks/CU) with issue-ahead.
// 4 waves (2x2). FUSED-N: columns >= nsplit route to C2 (fp32, ldc2).
// MODE: 0 plain, 1 split-K partial buffers, 2 batched over bz.
// ---------------------------------------------------------------------------
template <int BM, int BN, int MODE>
__global__ __launch_bounds__(256) void gemm_hl(
    const short* __restrict__ Ah, const short* __restrict__ Al,
    const short* __restrict__ Bh, const short* __restrict__ Bl,
    const float* __restrict__ bias, float* __restrict__ Cf,
    short* __restrict__ Ch, short* __restrict__ Cl, float* __restrict__ C2,
    int K, int ldc, int ldc2, int act, int kchunk, int nsplit, long bsA,
    long bsB, long bsBias, long bsC, long bsC2) {
  constexpr int MFR = BM / 16, NFR = BN / 16;
  constexpr int NA = 2 * MFR, NB = 2 * NFR, LPW = (NA + NB) / 4;
  constexpr int MF_W = MFR / 2, NF_W = NFR / 2;
  constexpr int ABUF = 2 * MFR * 512, BBUF = 2 * NFR * 512;
  __shared__ __align__(16) short As[2][2][MFR][512];
  __shared__ __align__(16) short Bs[2][2][NFR][512];
  int bx, by, bz;
  swz_block(bx, by, bz);
  const int t = threadIdx.x, w = t >> 6, lane = t & 63;
  const int lr = lane & 15, lg = lane >> 4;
  const int m0 = by * BM, n0 = bx * BN;
  const int kst = K >> 5;
  int k0 = 0;
  if (MODE == 1) {
    k0 = bz * kchunk;
    Cf += bz * bsC;
    C2 += bz * bsC2;
  }
  if (MODE == 2) {
    Ah += bz * bsA;
    Al += bz * bsA;
    Bh += bz * bsB;
    Bl += bz * bsB;
    if (bias) bias += bz * bsBias;
    Cf += bz * bsC;
  }
  const int nsteps = (MODE == 1 ? kchunk : K) >> 5;
  const int wmf = (w & 1) * MF_W, wnf = (w >> 1) * NF_W;

  const short* gp[LPW];
  short* lp[LPW];
  int bo[LPW], adv[LPW];
#pragma unroll
  for (int q = 0; q < LPW; q++) {
    int f = w * LPW + q;
    if (f < NA) {
      int p = f & 1, mf = f >> 1;
      gp[q] = (p ? Al : Ah) + (size_t)(m0 + mf * 16 + lr) * K + k0 + lg * 8;
      lp[q] = &As[0][p][mf][0];
      bo[q] = ABUF;
      adv[q] = 32;
    } else {
      int fb = f - NA, p = fb & 1, nf = fb >> 1;
      gp[q] = (p ? Bl : Bh) + ((size_t)(n0 / 16 + nf) * kst + (k0 >> 5)) * 512 +
              lane * 8;
      lp[q] = &Bs[0][p][nf][0];
      bo[q] = BBUF;
      adv[q] = 512;
    }
  }

  auto stage = [&](int bufidx) {
#pragma unroll
    for (int q = 0; q < LPW; q++) {
      g2l16(gp[q], lp[q] + bufidx * bo[q]);
      gp[q] += adv[q];
    }
  };

  fx4 acc[MF_W][NF_W];
#pragma unroll
  for (int i = 0; i < MF_W; i++)
#pragma unroll
    for (int j = 0; j < NF_W; j++) acc[i][j] = (fx4)0.f;

  stage(0);
  __syncthreads();

  int cur = 0;
  for (int s = 0; s < nsteps; s++) {
    if (s + 1 < nsteps) stage(cur ^ 1);
    s16x8 af[MF_W][2], bf[NF_W][2];
#pragma unroll
    for (int fm = 0; fm < MF_W; fm++) {
      af[fm][0] = *(const s16x8*)&As[cur][0][wmf + fm][lane * 8];
      af[fm][1] = *(const s16x8*)&As[cur][1][wmf + fm][lane * 8];
    }
#pragma unroll
    for (int fn = 0; fn < NF_W; fn++) {
      bf[fn][0] = *(const s16x8*)&Bs[cur][0][wnf + fn][lane * 8];
      bf[fn][1] = *(const s16x8*)&Bs[cur][1][wnf + fn][lane * 8];
    }
#pragma unroll
    for (int fm = 0; fm < MF_W; fm++)
#pragma unroll
      for (int fn = 0; fn < NF_W; fn++)
        acc[fm][fn] = __builtin_amdgcn_mfma_f32_16x16x32_bf16(
            af[fm][0], bf[fn][0], acc[fm][fn], 0, 0, 0);
#pragma unroll
    for (int fm = 0; fm < MF_W; fm++)
#pragma unroll
      for (int fn = 0; fn < NF_W; fn++)
        acc[fm][fn] = __builtin_amdgcn_mfma_f32_16x16x32_bf16(
            af[fm][0], bf[fn][1], acc[fm][fn], 0, 0, 0);
#pragma unroll
    for (int fm = 0; fm < MF_W; fm++)
#pragma unroll
      for (int fn = 0; fn < NF_W; fn++)
        acc[fm][fn] = __builtin_amdgcn_mfma_f32_16x16x32_bf16(
            af[fm][1], bf[fn][0], acc[fm][fn], 0, 0, 0);
    __syncthreads();
    cur ^= 1;
  }

  const int orow = (lane >> 4) * 4;
  const bool rg2 = (n0 >= nsplit);
#pragma unroll
  for (int fm = 0; fm < MF_W; fm++) {
#pragma unroll
    for (int fn = 0; fn < NF_W; fn++) {
      int col = n0 + (wnf + fn) * 16 + lr;
      if (MODE == 1) {
        if (rg2) {
          int c2 = col - nsplit;
#pragma unroll
          for (int j = 0; j < 4; j++) {
            int row = m0 + (wmf + fm) * 16 + orow + j;
            C2[(size_t)row * ldc2 + c2] = acc[fm][fn][j];
          }
        } else {
#pragma unroll
          for (int j = 0; j < 4; j++) {
            int row = m0 + (wmf + fm) * 16 + orow + j;
            Cf[(size_t)row * ldc + col] = acc[fm][fn][j];
          }
        }
      } else if (rg2) {
        int c2 = col - nsplit;
#pragma unroll
        for (int j = 0; j < 4; j++) {
          int row = m0 + (wmf + fm) * 16 + orow + j;
          C2[(size_t)row * ldc2 + c2] = acc[fm][fn][j];
        }
      } else {
        float bv = bias ? bias[col] : 0.f;
#pragma unroll
        for (int j = 0; j < 4; j++) {
          int row = m0 + (wmf + fm) * 16 + orow + j;
          float v = acc[fm][fn][j] + bv;
          if (act) v = gelu_f(v);
          size_t idx = (size_t)row * ldc + col;
          if (Cf) Cf[idx] = v;
          if (Ch) {
            unsigned short hb = f2bf_u(v);
            Ch[idx] = (short)hb;
            Cl[idx] = (short)f2bf_u(v - bfu2f(hb));
          }
        }
      }
    }
  }
}

// ---------- weight packing ----------
__device__ __forceinline__ void pack_store(const float* src, short* ph,
                                           short* pl, size_t o) {
  float4 a = *(const float4*)src;
  float4 b = *(const float4*)(src + 4);
  float v[8] = {a.x, a.y, a.z, a.w, b.x, b.y, b.z, b.w};
  s16x8 hv, lv;
#pragma unroll
  for (int e = 0; e < 8; e++) {
    unsigned short h = f2bf_u(v[e]);
    hv[e] = (short)h;
    lv[e] = (short)f2bf_u(v[e] - bfu2f(h));
  }
  *(s16x8*)(ph + o) = hv;
  *(s16x8*)(pl + o) = lv;
}

// One dispatch packs all per-layer weight matrices. Tiles:
// [0,3456)       QKV       [3456,4608)  Wao   [4608,9216)  Wi
// [9216,13824)   Wo
// even-layer extras (grid extended):
// [13824,14016)  LoRA-up pad   [14016,14784) LoRA-dn pad
// [14784,22848)  cW1
__global__ __launch_bounds__(256) void pack_layer_k(
    const float* __restrict__ Wq, const float* __restrict__ Wk,
    const float* __restrict__ Wv, const float* __restrict__ Wao,
    const float* __restrict__ Wi, const float* __restrict__ Wo,
    const float* __restrict__ Aup, const float* __restrict__ Adn,
    const float* __restrict__ cW1, short* __restrict__ qph,
    short* __restrict__ qpl, short* __restrict__ aph, short* __restrict__ apl,
    short* __restrict__ iph, short* __restrict__ ipl, short* __restrict__ oph,
    short* __restrict__ opl, short* __restrict__ luph, short* __restrict__ lupl,
    short* __restrict__ ldph, short* __restrict__ ldpl,
    short* __restrict__ c1ph, short* __restrict__ c1pl) {
  int tile = blockIdx.x * 4 + (threadIdx.x >> 6);
  int lane = threadIdx.x & 63;
  int lr = lane & 15, lg = lane >> 4;
  const float* src;
  short *ph, *pl;
  size_t o;
  if (tile < 3456) {
    int nf = tile / 24, ks = tile % 24;
    int row = nf * 16 + lr;
    const float* W = row < 768 ? Wq : row < 1536 ? Wk : Wv;
    int r = row < 768 ? row : row < 1536 ? row - 768 : row - 1536;
    src = W + (size_t)r * 768 + ks * 32 + lg * 8;
    ph = qph; pl = qpl;
    o = (size_t)tile * 512 + lane * 8;
  } else if (tile < 4608) {
    int idx = tile - 3456;
    int nf = idx / 24, ks = idx % 24;
    src = Wao + (size_t)(nf * 16 + lr) * 768 + ks * 32 + lg * 8;
    ph = aph; pl = apl;
    o = (size_t)idx * 512 + lane * 8;
  } else if (tile < 9216) {
    int idx = tile - 4608;
    int nf = idx / 24, ks = idx % 24;
    src = Wi + (size_t)(nf * 16 + lr) * 768 + ks * 32 + lg * 8;
    ph = iph; pl = ipl;
    o = (size_t)idx * 512 + lane * 8;
  } else if (tile < 13824) {
    int idx = tile - 9216;
    int nf = idx / 96, ks = idx % 96;
    src = Wo + (size_t)(nf * 16 + lr) * 3072 + ks * 32 + lg * 8;
    ph = oph; pl = opl;
    o = (size_t)idx * 512 + lane * 8;
  } else if (tile < 14016) {
    int idx = tile - 13824;  // LoRA-up pad: 8 nfrags x 24 ksteps, rows>=120 -> 0
    int nf = idx / 24, ks = idx % 24;
    int row = nf * 16 + lr;
    o = (size_t)idx * 512 + lane * 8;
    if (row < 120) {
      pack_store(Aup + (size_t)row * 768 + ks * 32 + lg * 8, luph, lupl, o);
    } else {
      *(s16x8*)(luph + o) = (s16x8)0;
      *(s16x8*)(lupl + o) = (s16x8)0;
    }
    return;
  } else if (tile < 14784) {
    int idx = tile - 14016;  // LoRA-dn pad: 8 x 96
    int nf = idx / 96, ks = idx % 96;
    int row = nf * 16 + lr;
    o = (size_t)idx * 512 + lane * 8;
    if (row < 120) {
      pack_store(Adn + (size_t)row * 3072 + ks * 32 + lg * 8, ldph, ldpl, o);
    } else {
      *(s16x8*)(ldph + o) = (s16x8)0;
      *(s16x8*)(ldpl + o) = (s16x8)0;
    }
    return;
  } else {
    int idx = tile - 14784;  // cW1: 336 nfrags x 24 ksteps
    int nf = idx / 24, ks = idx % 24;
    src = cW1 + (size_t)(nf * 16 + lr) * 768 + ks * 32 + lg * 8;
    ph = c1ph; pl = c1pl;
    o = (size_t)idx * 512 + lane * 8;
  }
  pack_store(src, ph, pl, o);
}

// packs all 12 layers' [bq|bk|bv] into qb[12][2304]
__global__ __launch_bounds__(256) void pack_bias_k(const float* __restrict__ bq,
                                                   const float* __restrict__ bk,
                                                   const float* __restrict__ bv,
                                                   float* __restrict__ qb) {
  int idx = blockIdx.x * 256 + threadIdx.x;
  if (idx >= 12 * kQKV) return;
  int i = idx / kQKV, c = idx % kQKV;
  float v = (c < 768)    ? bq[i * 768 + c]
            : (c < 1536) ? bk[i * 768 + c - 768]
                         : bv[i * 768 + c - 1536];
  qb[idx] = v;
}

__global__ __launch_bounds__(256) void concat_k(const float* __restrict__ rf,
                                                const float* __restrict__ cls,
                                                float* __restrict__ h) {
  int idx = blockIdx.x * 256 + threadIdx.x;
  if (idx >= kRows * kD) return;
  int d = idx % kD;
  int row = idx / kD;
  int s = row % kS;
  int b = row / kS;
  h[idx] = (s == 0) ? cls[d] : rf[((long)b * kSR + (s - 1)) * kD + d];
}

__global__ void cc_k(const float* __restrict__ mask, float* __restrict__ cc) {
  int d = threadIdx.x;
  if (d < kND) {
    float s = 0.f;
    for (int r = 0; r < kSR; r++) s += mask[r * kND + d];
    cc[d] = s;
  }
}

__global__ __launch_bounds__(256) void mmat_k(const float* __restrict__ Adn,
                                              const float* __restrict__ Bup,
                                              float* __restrict__ Mm) {
  int g = blockIdx.x;
  int t = threadIdx.x;
  int pair = t & 63;
  int quarter = t >> 6;
  int rp = pair >> 3, r = pair & 7;
  const float* ad = Adn + (long)(g * 8 + rp) * kH;
  const float* bu = Bup + (long)g * kH * 8 + r;
  float acc = 0.f;
  for (int hh = quarter * 768; hh < quarter * 768 + 768; hh++)
    acc += ad[hh] * bu[hh * 8];
  __shared__ float red[256];
  red[t] = acc;
  __syncthreads();
  if (t < 64) Mm[g * 64 + pair] = red[t] + red[t + 64] + red[t + 128] + red[t + 192];
}

// plain LN(x) -> hi/lo planes (layer 0 only)
__global__ __launch_bounds__(256) void ln_bf_k(const float* __restrict__ x,
                                               const float* __restrict__ g,
                                               const float* __restrict__ b,
                                               short* __restrict__ yh,
                                               short* __restrict__ yl,
                                               float eps) {
  int row = blockIdx.x;
  int t = threadIdx.x;
  long rb = (long)row * kD;
  float v0 = x[rb + t], v1 = x[rb + t + 256], v2 = x[rb + t + 512];
  float m = block_sum(v0 + v1 + v2) * (1.0f / 768.0f);
  float d0 = v0 - m, d1 = v1 - m, d2 = v2 - m;
  float q = block_sum(d0 * d0 + d1 * d1 + d2 * d2);
  float inv = rsqrtf(q * (1.0f / 768.0f) + eps);
#pragma unroll
  for (int c = 0; c < 3; c++) {
    int tt = t + c * 256;
    float dd = (c == 0 ? d0 : c == 1 ? d1 : d2);
    float val = dd * inv * g[tt] + b[tt];
    unsigned short hb = f2bf_u(val);
    yh[rb + tt] = (short)hb;
    yl[rb + tt] = (short)f2bf_u(val - bfu2f(hb));
  }
}

// odd layers: h = sum4(cwop) + bo + res1 ; n1 = LN(h) -> planes
__global__ __launch_bounds__(256) void ln_parts_k(
    const float* __restrict__ parts, const float* __restrict__ b2,
    const float* __restrict__ r2, float* __restrict__ hout,
    const float* __restrict__ g, const float* __restrict__ b,
    short* __restrict__ yh, short* __restrict__ yl, float eps) {
  int row = blockIdx.x;
  int t = threadIdx.x;
  long rb = (long)row * kD;
  float v0, v1, v2;
  {
    float s0 = 0, s1 = 0, s2 = 0;
#pragma unroll
    for (int p = 0; p < 4; p++) {
      s0 += parts[p * kPS + rb + t];
      s1 += parts[p * kPS + rb + t + 256];
      s2 += parts[p * kPS + rb + t + 512];
    }
    v0 = s0 + b2[t] + r2[rb + t];
    v1 = s1 + b2[t + 256] + r2[rb + t + 256];
    v2 = s2 + b2[t + 512] + r2[rb + t + 512];
  }
  hout[rb + t] = v0;
  hout[rb + t + 256] = v1;
  hout[rb + t + 512] = v2;
  float m = block_sum(v0 + v1 + v2) * (1.0f / 768.0f);
  float d0 = v0 - m, d1 = v1 - m, d2 = v2 - m;
  float q = block_sum(d0 * d0 + d1 * d1 + d2 * d2);
  float inv = rsqrtf(q * (1.0f / 768.0f) + eps);
#pragma unroll
  for (int c = 0; c < 3; c++) {
    int tt = t + c * 256;
    float dd = (c == 0 ? d0 : c == 1 ? d1 : d2);
    float val = dd * inv * g[tt] + b[tt];
    unsigned short hb = f2bf_u(val);
    yh[rb + tt] = (short)hb;
    yl[rb + tt] = (short)f2bf_u(val - bfu2f(hb));
  }
}

// final: out = LN(sum4(cwop) + bo + res1)
__global__ __launch_bounds__(256) void ln_row_k(
    const float* __restrict__ parts, const float* __restrict__ b2,
    const float* __restrict__ r2, const float* __restrict__ g,
    const float* __restrict__ b, float* __restrict__ y, float eps) {
  int row = blockIdx.x;
  int t = threadIdx.x;
  long rb = (long)row * kD;
  float s0 = 0, s1 = 0, s2 = 0;
#pragma unroll
  for (int p = 0; p < 4; p++) {
    s0 += parts[p * kPS + rb + t];
    s1 += parts[p * kPS + rb + t + 256];
    s2 += parts[p * kPS + rb + t + 512];
  }
  float v0 = s0 + b2[t] + r2[rb + t];
  float v1 = s1 + b2[t + 256] + r2[rb + t + 256];
  float v2 = s2 + b2[t + 512] + r2[rb + t + 512];
  float m = block_sum(v0 + v1 + v2) * (1.0f / 768.0f);
  float d0 = v0 - m, d1 = v1 - m, d2 = v2 - m;
  float q = block_sum(d0 * d0 + d1 * d1 + d2 * d2);
  float inv = rsqrtf(q * (1.0f / 768.0f) + eps);
  y[rb + t] = d0 * inv * g[t] + b[t];
  y[rb + t + 256] = d1 * inv * g[t + 256] + b[t + 256];
  y[rb + t + 512] = d2 * inv * g[t + 512] + b[t + 512];
}

// res1 = sum2(aop) + abias + h ; n2 = LN(res1) -> planes
__global__ __launch_bounds__(256) void addln_bf_k(
    const float* __restrict__ aparts, const float* __restrict__ abias,
    const float* __restrict__ hh, const float* __restrict__ g,
    const float* __restrict__ b, float* __restrict__ r1,
    short* __restrict__ n2h, short* __restrict__ n2l, float eps) {
  int row = blockIdx.x;
  int t = threadIdx.x;
  long rb = (long)row * kD;
  float v0 = aparts[rb + t] + aparts[kPS + rb + t] + abias[t] + hh[rb + t];
  float v1 = aparts[rb + t + 256] + aparts[kPS + rb + t + 256] + abias[t + 256] +
             hh[rb + t + 256];
  float v2 = aparts[rb + t + 512] + aparts[kPS + rb + t + 512] + abias[t + 512] +
             hh[rb + t + 512];
  r1[rb + t] = v0;
  r1[rb + t + 256] = v1;
  r1[rb + t + 512] = v2;
  float m = block_sum(v0 + v1 + v2) * (1.0f / 768.0f);
  float d0 = v0 - m, d1 = v1 - m, d2 = v2 - m;
  float q = block_sum(d0 * d0 + d1 * d1 + d2 * d2);
  float inv = rsqrtf(q * (1.0f / 768.0f) + eps);
#pragma unroll
  for (int c = 0; c < 3; c++) {
    int tt = t + c * 256;
    float dd = (c == 0 ? d0 : c == 1 ? d1 : d2);
    float val = dd * inv * g[tt] + b[tt];
    unsigned short hb = f2bf_u(val);
    n2h[rb + tt] = (short)hb;
    n2l[rb + tt] = (short)f2bf_u(val - bfu2f(hb));
  }
}

// One block per (b, head). Reads qkv [1920][2304] (biases already applied
// in the QKV GEMM epilogue).
__global__ __launch_bounds__(256) void attn_k(const float* __restrict__ qkv,
                                              short* __restrict__ oh,
                                              short* __restrict__ ol) {
  int blk = blockIdx.x;
  int b = blk / kNH, hh = blk % kNH;
  __shared__ float qs[30][65], ks[30][65], vs[30][65], ps[30][32];
  int t = threadIdx.x;
  long ibase = (long)b * kS * kQKV + hh * 64;
  long obase = (long)b * kS * kD + hh * 64;
  for (int idx = t; idx < 1920; idx += 256) {
    int s = idx >> 6, d = idx & 63;
    long a = ibase + (long)s * kQKV + d;
    qs[s][d] = qkv[a];
    ks[s][d] = qkv[a + 768];
    vs[s][d] = qkv[a + 1536];
  }
  __syncthreads();
  for (int idx = t; idx < 900; idx += 256) {
    int r = idx / 30, c = idx % 30;
    float acc = 0.f;
#pragma unroll
    for (int d = 0; d < 64; d++) acc += qs[r][d] * ks[c][d];
    ps[r][c] = acc * 0.125f;
  }
  __syncthreads();
  if (t < 30) {
    float mx = -1e30f;
#pragma unroll
    for (int c = 0; c < 30; c++) mx = fmaxf(mx, ps[t][c]);
    float sm = 0.f;
#pragma unroll
    for (int c = 0; c < 30; c++) sm += expf(ps[t][c] - mx);
    float inv = 1.0f / sm;
#pragma unroll
    for (int c = 0; c < 30; c++) ps[t][c] = expf(ps[t][c] - mx) * inv;
  }
  __syncthreads();
  for (int idx = t; idx < 1920; idx += 256) {
    int r = idx >> 6, d = idx & 63;
    float acc = 0.f;
#pragma unroll
    for (int c = 0; c < 30; c++) acc += ps[r][c] * vs[c][d];
    long a = obase + (long)r * kD + d;
    unsigned short hb = f2bf_u(acc);
    oh[a] = (short)hb;
    ol[a] = (short)f2bf_u(acc - bfu2f(hb));
  }
}

// pooled (row d*64+b) = (sum_r mask*sum2(aop))/cc + bao -> hi/lo planes
__global__ __launch_bounds__(256) void pool_k(const float* __restrict__ aparts,
                                              const float* __restrict__ bao,
                                              const float* __restrict__ mask,
                                              const float* __restrict__ cc,
                                              short* __restrict__ ph,
                                              short* __restrict__ pl) {
  int blk = blockIdx.x;
  int d = blk >> 6, b = blk & 63;
  __shared__ float mr[32];
  int t = threadIdx.x;
  if (t < kSR) mr[t] = mask[t * kND + d];
  __syncthreads();
  float inv = 1.0f / cc[d];
  for (int hd = t; hd < kD; hd += 256) {
    float acc = 0.f;
    for (int r = 0; r < kSR; r++) {
      long o = ((long)b * kS + 1 + r) * kD + hd;
      acc += mr[r] * (aparts[o] + aparts[kPS + o]);
    }
    float v = acc * inv + bao[hd];
    unsigned short hb = f2bf_u(v);
    size_t o = (size_t)blk * kD + hd;
    ph[o] = (short)hb;
    pl[o] = (short)f2bf_u(v - bfu2f(hb));
  }
}

__global__ __launch_bounds__(256) void cls2_k(const float* __restrict__ z,
                                              const float* __restrict__ lng,
                                              const float* __restrict__ lnb,
                                              const float* __restrict__ w2,
                                              const float* __restrict__ b2,
                                              float* __restrict__ da) {
  int blk = blockIdx.x;
  int d = blk >> 6, b = blk & 63;
  int t = threadIdx.x;
  const float* zr = z + (long)blk * 384;
  float v0 = zr[t];
  float v1 = (t < 128) ? zr[256 + t] : 0.f;
  float m = block_sum(v0 + v1) * (1.0f / 384.0f);
  float d0 = v0 - m;
  float d1 = (t < 128) ? v1 - m : 0.f;
  float q = block_sum(d0 * d0 + d1 * d1);
  float inv = rsqrtf(q * (1.0f / 384.0f) + 1e-5f);
  const float* lg = lng + (long)d * 384;
  const float* lb = lnb + (long)d * 384;
  const float* wd = w2 + (long)d * 384;
  float p = gelu_f(d0 * inv * lg[t] + lb[t]) * wd[t];
  if (t < 128) p += gelu_f(d1 * inv * lg[256 + t] + lb[256 + t]) * wd[256 + t];
  float ps = block_sum(p);
  if (t == 0) da[b * kND + d] = (ps + b2[d] > 0.f) ? 1.f : 0.f;
}

// even layers: vv computed inline (sum4(iap) + SCALE*M_e@u);
// base = sum4(cwop)+bo; expert loop; h = acc+res1; then fused next-layer LN.
__global__ __launch_bounds__(256) void finaleven_k(
    const float* __restrict__ parts, const float* __restrict__ bo,
    const float* __restrict__ res1, const float* __restrict__ ub,
    const float* __restrict__ iap, const float* __restrict__ Mm,
    const float* __restrict__ Bd, const float* __restrict__ da,
    const float* __restrict__ mask, float* __restrict__ h,
    const float* __restrict__ g1, const float* __restrict__ b1,
    short* __restrict__ n1h, short* __restrict__ n1l) {
  int row = blockIdx.x;
  int b = row / kS, s = row % kS;
  int t = threadIdx.x;
  __shared__ float w[16];
  __shared__ float vvs[120];
  long rbl = (long)row * 128;
  if (t < 120) {
    int e = t >> 3, rp = t & 7;
    const float* Me = Mm + e * 64 + rp * 8;
    float acc = 0.f;
#pragma unroll
    for (int p = 0; p < 4; p++) acc += iap[p * kPSL + rbl + t];
    const float* ur = ub + rbl + e * 8;
#pragma unroll
    for (int r = 0; r < 8; r++) acc += 2.0f * Me[r] * ur[r];
    vvs[t] = acc;
  }
  if (t < kND) w[t] = (s >= 1) ? da[b * kND + t] * mask[(s - 1) * kND + t] : 0.f;
  if (t == kND) w[kND] = 1.f;
  __syncthreads();
  float wsum = 0.f;
#pragma unroll
  for (int e = 0; e < kE; e++) wsum += w[e];
  float winv = 1.0f / wsum;
  long rb = (long)row * kD;
  float b0 = bo[t], b1v = bo[t + 256], b2v = bo[t + 512];
#pragma unroll
  for (int p = 0; p < 4; p++) {
    b0 += parts[p * kPS + rb + t];
    b1v += parts[p * kPS + rb + t + 256];
    b2v += parts[p * kPS + rb + t + 512];
  }
  float a0 = 0.f, a1 = 0.f, a2 = 0.f;
  for (int e = 0; e < kE; e++) {
    float we = w[e];
    if (we == 0.f) continue;
    const float* vr = vvs + e * 8;
    float y0 = b0 + 2.0f * dot8(Bd + ((long)(e * kD + t)) * 8, vr);
    float y1 = b1v + 2.0f * dot8(Bd + ((long)(e * kD + t + 256)) * 8, vr);
    float y2 = b2v + 2.0f * dot8(Bd + ((long)(e * kD + t + 512)) * 8, vr);
    float m = block_sum(y0 + y1 + y2) * (1.0f / 768.0f);
    float d0 = y0 - m, d1 = y1 - m, d2 = y2 - m;
    float q = block_sum(d0 * d0 + d1 * d1 + d2 * d2);
    float inv = rsqrtf(q * (1.0f / 768.0f) + 1e-5f);
    float sc = we * winv * inv;
    a0 += sc * d0;
    a1 += sc * d1;
    a2 += sc * d2;
  }
  float v0 = a0 + res1[rb + t];
  float v1 = a1 + res1[rb + t + 256];
  float v2 = a2 + res1[rb + t + 512];
  h[rb + t] = v0;
  h[rb + t + 256] = v1;
  h[rb + t + 512] = v2;
  float m = block_sum(v0 + v1 + v2) * (1.0f / 768.0f);
  float d0 = v0 - m, d1 = v1 - m, d2 = v2 - m;
  float q = block_sum(d0 * d0 + d1 * d1 + d2 * d2);
  float inv = rsqrtf(q * (1.0f / 768.0f) + 1e-12f);
#pragma unroll
  for (int c = 0; c < 3; c++) {
    int tt = t + c * 256;
    float dd = (c == 0 ? d0 : c == 1 ? d1 : d2);
    float val = dd * inv * g1[tt] + b1[tt];
    unsigned short hb = f2bf_u(val);
    n1h[rb + tt] = (short)hb;
    n1l[rb + tt] = (short)f2bf_u(val - bfu2f(hb));
  }
}

}  // namespace

extern "C" void kernel_launch(void* const* d_in, const int* in_sizes, int n_in,
                              void* d_out, int out_size, void* d_ws, size_t ws_size,
                              hipStream_t stream) {
  const float* region = (const float*)d_in[0];
  const float* mask = (const float*)d_in[1];
  const float* cls = (const float*)d_in[2];
  const float* ln1g = (const float*)d_in[3];
  const float* ln1b = (const float*)d_in[4];
  const float* ln2g = (const float*)d_in[5];
  const float* ln2b = (const float*)d_in[6];
  const float* Wq = (const float*)d_in[7];
  const float* bq = (const float*)d_in[8];
  const float* Wk = (const float*)d_in[9];
  const float* bk = (const float*)d_in[10];
  const float* Wv = (const float*)d_in[11];
  const float* bv = (const float*)d_in[12];
  const float* Wao = (const float*)d_in[13];
  const float* bao = (const float*)d_in[14];
  const float* Wi = (const float*)d_in[15];
  const float* bi = (const float*)d_in[16];
  const float* Wo = (const float*)d_in[17];
  const float* bo = (const float*)d_in[18];
  const float* fg = (const float*)d_in[19];
  const float* fb = (const float*)d_in[20];
  const float* cW1 = (const float*)d_in[21];
  const float* cb1 = (const float*)d_in[22];
  const float* clng = (const float*)d_in[23];
  const float* clnb = (const float*)d_in[24];
  const float* cW2 = (const float*)d_in[25];
  const float* cb2 = (const float*)d_in[26];
  const float* Aup = (const float*)d_in[27];
  const float* Bup = (const float*)d_in[28];
  const float* Adn = (const float*)d_in[29];
  const float* Bdn = (const float*)d_in[30];
  float* out = (float*)d_out;

  char* wsb = (char*)d_ws;
  size_t off = 0;
  auto alloc = [&](size_t bytes) {
    char* p = wsb + off;
    off = (off + bytes + 255) & ~(size_t)255;
    return (void*)p;
  };
  float* h = (float*)alloc((size_t)kRows * kD * 4);
  float* qkv = (float*)alloc((size_t)kRows * kQKV * 4);
  float* aop = (float*)alloc((size_t)2 * kRows * kD * 4);     // Wao partials
  float* res1 = (float*)alloc((size_t)kRows * kD * 4);
  float* cwop = (float*)alloc((size_t)4 * kRows * kD * 4);    // Wo partials
  float* zb = (float*)alloc((size_t)kND * kB * 384 * 4);
  float* da = (float*)alloc((size_t)kB * kND * 4);
  float* ub = (float*)alloc((size_t)kRows * 128 * 4);         // lora-up (full)
  float* iap = (float*)alloc((size_t)4 * kRows * 128 * 4);    // lora-dn parts
  float* Mm = (float*)alloc((size_t)kNE * kE * 64 * 4);
  float* cc = (float*)alloc(64);
  float* qkvbias = (float*)alloc((size_t)12 * kQKV * 4);
  short* n1h = (short*)alloc((size_t)kRows * kD * 2);
  short* n1l = (short*)alloc((size_t)kRows * kD * 2);
  short* n2h = (short*)alloc((size_t)kRows * kD * 2);
  short* n2l = (short*)alloc((size_t)kRows * kD * 2);
  short* inth = (short*)alloc((size_t)kRows * kH * 2);
  short* intl = (short*)alloc((size_t)kRows * kH * 2);
  short* pooledh = (short*)alloc((size_t)kND * kB * kD * 2);
  short* pooledl = (short*)alloc((size_t)kND * kB * kD * 2);
  // packed weights (frag-linear). wi/wo buffers carry lora tails (fused N).
  short* qkvph = (short*)alloc((size_t)144 * 24 * 512 * 2);
  short* qkvpl = (short*)alloc((size_t)144 * 24 * 512 * 2);
  short* waoph = (short*)alloc((size_t)48 * 24 * 512 * 2);
  short* waopl = (short*)alloc((size_t)48 * 24 * 512 * 2);
  short* wiph = (short*)alloc((size_t)200 * 24 * 512 * 2);   // 192 wi + 8 lu
  short* wipl = (short*)alloc((size_t)200 * 24 * 512 * 2);
  short* woph = (short*)alloc((size_t)56 * 96 * 512 * 2);    // 48 wo + 8 ld
  short* wopl = (short*)alloc((size_t)56 * 96 * 512 * 2);
  short* cw1ph = (short*)alloc((size_t)336 * 24 * 512 * 2);
  short* cw1pl = (short*)alloc((size_t)336 * 24 * 512 * 2);
  short* luph = wiph + (size_t)192 * 24 * 512;
  short* lupl = wipl + (size_t)192 * 24 * 512;
  short* ldph = woph + (size_t)48 * 96 * 512;
  short* ldpl = wopl + (size_t)48 * 96 * 512;

  concat_k<<<(kRows * kD + 255) / 256, 256, 0, stream>>>(region, cls, h);
  cc_k<<<1, 32, 0, stream>>>(mask, cc);
  mmat_k<<<kNE * kE, 256, 0, stream>>>(Adn, Bup, Mm);
  pack_bias_k<<<(12 * kQKV + 255) / 256, 256, 0, stream>>>(bq, bk, bv, qkvbias);

  const int nDD = kD * kD;
  const int nDH = kD * kH;

  ln_bf_k<<<kRows, 256, 0, stream>>>(h, ln1g, ln1b, n1h, n1l, 1e-12f);

  for (int i = 0; i < kL; i++) {
    int le = i >> 1;
    bool even = (i % 2) == 0;
    // one packing dispatch per layer (even layers pack lora+cw1 tails too)
    pack_layer_k<<<even ? 5712 : 3456, 256, 0, stream>>>(
        Wq + (long)i * nDD, Wk + (long)i * nDD, Wv + (long)i * nDD,
        Wao + (long)i * nDD, Wi + (long)i * nDH, Wo + (long)i * nDH,
        Aup + (long)le * kE * 8 * kD, Adn + (long)le * kE * 8 * kH,
        cW1 + (long)le * kND * 384 * kD, qkvph, qkvpl, waoph, waopl, wiph,
        wipl, woph, wopl, luph, lupl, ldph, ldpl, cw1ph, cw1pl);

    // QKV (N=2304, bias in epilogue): 36x30 = 1080 blocks
    gemm_hl<64, 64, 0><<<dim3(36, 30), 256, 0, stream>>>(
        n1h, n1l, qkvph, qkvpl, qkvbias + (long)i * kQKV, qkv, nullptr, nullptr,
        nullptr, 768, kQKV, 0, 0, 0, kBIG, 0, 0, 0, 0, 0);
    attn_k<<<kB * kNH, 256, 0, stream>>>(qkv, n1h, n1l);
    // Wao split-K x2: 12x30x2 = 720 blocks
    gemm_hl<64, 64, 1><<<dim3(12, 30, 2), 256, 0, stream>>>(
        n1h, n1l, waoph, waopl, nullptr, aop, nullptr, nullptr, nullptr, 768,
        kD, 0, 0, 384, kBIG, 0, 0, 0, kPS, 0);
    addln_bf_k<<<kRows, 256, 0, stream>>>(aop, bao + i * kD, h, ln2g + i * kD,
                                          ln2b + i * kD, res1, n2h, n2l, 1e-12f);
    // Wi (+ fused LoRA-up on even layers): N=3200 or 3072 -> 50/48 x 30
    gemm_hl<64, 64, 0><<<dim3(even ? 50 : 48, 30), 256, 0, stream>>>(
        n2h, n2l, wiph, wipl, bi + i * kH, nullptr, inth, intl, ub, 768, kH,
        128, 1, 0, even ? 3072 : kBIG, 0, 0, 0, 0, 0);
    // Wo (+ fused LoRA-down on even layers), split-K x4: 14/12 x 30 x 4
    gemm_hl<64, 64, 1><<<dim3(even ? 14 : 12, 30, 4), 256, 0, stream>>>(
        inth, intl, woph, wopl, nullptr, cwop, nullptr, nullptr, iap, 3072, kD,
        128, 0, 768, even ? 768 : kBIG, 0, 0, 0, kPS, kPSL);
    if (even) {
      pool_k<<<kND * kB, 256, 0, stream>>>(aop, bao + i * kD, mask, cc, pooledh,
                                           pooledl);
      // batched classifier GEMM: per disease d, M=64, N=384, K=768
      gemm_hl<64, 64, 2><<<dim3(6, 1, 14), 256, 0, stream>>>(
          pooledh, pooledl, cw1ph, cw1pl, cb1 + (long)le * kND * 384, zb,
          nullptr, nullptr, nullptr, 768, 384, 0, 0, 0, kBIG, (long)64 * kD,
          (long)576 * 512, 384, (long)64 * 384, 0);
      cls2_k<<<kND * kB, 256, 0, stream>>>(zb, clng + (long)le * kND * 384,
                                           clnb + (long)le * kND * 384,
                                           cW2 + (long)le * kND * 384,
                                           cb2 + le * kND, da);
      finaleven_k<<<kRows, 256, 0, stream>>>(
          cwop, bo + i * kD, res1, ub, iap, Mm + le * kE * 64,
          Bdn + (long)le * kE * kD * 8, da, mask, h, ln1g + (i + 1) * kD,
          ln1b + (i + 1) * kD, n1h, n1l);
    } else if (i < kL - 1) {
      ln_parts_k<<<kRows, 256, 0, stream>>>(cwop, bo + i * kD, res1, h,
                                            ln1g + (i + 1) * kD,
                                            ln1b + (i + 1) * kD, n1h, n1l,
                                            1e-12f);
    } else {
      ln_row_k<<<kRows, 256, 0, stream>>>(cwop, bo + i * kD, res1, fg, fb, out,
                                          1e-12f);
    }
  }
}